// Round 4
// baseline (508.880 us; speedup 1.0000x reference)
//
#include <hip/hip_runtime.h>
#include <hip/hip_bf16.h>

#define N_NODES 50000
#define N_EDGES 800000
#define IN_DIM 256
#define OUT_DIM 64
#define HEADS 4
#define HD 256          // HEADS*OUT_DIM
#define P_L 0.1f
#define TILE_N 16
#define CN 4
#define CAP 64          // per-node edge bucket capacity (expected max deg ~43)
#define OVCAP 4096      // overflow list capacity

// ---------------- precompute: fold W_att/b_att into W_g ----------------
__global__ __launch_bounds__(256) void precompute_kernel(
    const float* __restrict__ W_att, const float* __restrict__ b_att,
    const float* __restrict__ W_g,
    float* __restrict__ v_dst, float* __restrict__ v_src,
    float* __restrict__ c_dst, float* __restrict__ c_src) {
    int t = threadIdx.x;          // 0..255
    int h = t >> 6, dd = t & 63;
    float sd = 0.f, ss = 0.f;
    for (int e = 0; e < 64; ++e) {
        float w = W_att[h * 4096 + dd * 64 + e];
        sd += w * W_g[h * 128 + e];
        ss += w * W_g[h * 128 + 64 + e];
    }
    v_dst[t] = sd;
    v_src[t] = ss;
    if (dd == 0) {
        float cd = 0.f, cs = 0.f;
        for (int e = 0; e < 64; ++e) {
            float b = b_att[h * 64 + e];
            cd += b * W_g[h * 128 + e];
            cs += b * W_g[h * 128 + 64 + e];
        }
        c_dst[h] = cd;
        c_src[h] = cs;
    }
}

// ---------------- node transform: hh = relu(h@W_in+b), gd/gs ----------------
// h rows are read with wave-uniform addresses -> scalar loads (SGPR), so the
// VALU only does v_fmac acc, s_h, v_w. No LDS at all.
__global__ __launch_bounds__(256) void node_kernel(
    const float* __restrict__ hin,
    const float* __restrict__ W_in, const float* __restrict__ b_in,
    const float* __restrict__ v_dst, const float* __restrict__ v_src,
    const float* __restrict__ c_dst, const float* __restrict__ c_src,
    __hip_bfloat16* __restrict__ hh, float* __restrict__ gd,
    float* __restrict__ gs) {
    int t = threadIdx.x;
    int n0 = blockIdx.x * TILE_N;

    float acc[TILE_N];
    float bb = b_in[t];
    #pragma unroll
    for (int i = 0; i < TILE_N; ++i) acc[i] = bb;

    for (int k = 0; k < IN_DIM; k += 4) {
        float w0 = W_in[(k + 0) * HD + t];
        float w1 = W_in[(k + 1) * HD + t];
        float w2 = W_in[(k + 2) * HD + t];
        float w3 = W_in[(k + 3) * HD + t];
        #pragma unroll
        for (int i = 0; i < TILE_N; ++i) {
            // wave-uniform address -> s_load_dwordx4
            float4 hv = *(const float4*)(hin + (size_t)(n0 + i) * IN_DIM + k);
            acc[i] += hv.x * w0 + hv.y * w1 + hv.z * w2 + hv.w * w3;
        }
    }

    #pragma unroll
    for (int i = 0; i < TILE_N; ++i) {
        acc[i] = fmaxf(acc[i], 0.f);
        hh[(size_t)(n0 + i) * HD + t] = __float2bfloat16(acc[i]);
    }

    // gd/gs: t = head*64 + d; wave w handles head w
    int head = t >> 6, lane = t & 63;
    float vd = v_dst[t];
    float vs = v_src[t];
    float cd = c_dst[head], cs = c_src[head];
    for (int i = 0; i < TILE_N; ++i) {
        float pd = acc[i] * vd;
        float ps = acc[i] * vs;
        #pragma unroll
        for (int off = 32; off; off >>= 1) {
            pd += __shfl_xor(pd, off, 64);
            ps += __shfl_xor(ps, off, 64);
        }
        if (lane == 0) {
            gd[(n0 + i) * HEADS + head] = pd + cd;
            gs[(n0 + i) * HEADS + head] = ps + cs;
        }
    }
}

// ---------------- bucket fill: group SRC node ids by dst ----------------
__global__ __launch_bounds__(256) void fill_kernel(
    const int* __restrict__ src, const int* __restrict__ dst,
    int* __restrict__ cursor, int* __restrict__ bucket_src,
    int* __restrict__ ov_list, int* __restrict__ ov_count) {
    int e = blockIdx.x * 256 + threadIdx.x;
    if (e >= N_EDGES) return;
    int n = dst[e];
    int pos = atomicAdd(&cursor[n], 1);
    if (pos < CAP) {
        bucket_src[(size_t)n * CAP + pos] = src[e];
    } else {
        int oi = atomicAdd(ov_count, 1);
        if (oi < OVCAP) ov_list[oi] = e;
    }
}

// ---------------- gather aggregation: z[n] = sum over in-edges ----------------
__global__ __launch_bounds__(256) void agg_kernel(
    const int* __restrict__ bucket_src, const int* __restrict__ cursor,
    const float* __restrict__ dnorm, const float* __restrict__ b_g,
    const __hip_bfloat16* __restrict__ hh, const float* __restrict__ gd,
    const float* __restrict__ gs, float* __restrict__ z) {
    __shared__ int s_lds[CAP];
    __shared__ float alpha_lds[CAP][HEADS];
    int n = blockIdx.x;
    int t = threadIdx.x;
    int deg = cursor[n];
    if (deg > CAP) deg = CAP;
    float dn = dnorm[n];

    // phase 1: per-edge alphas in parallel. thread t = edge (t>>2), head (t&3).
    int ei = t >> 2, hd = t & 3;
    if (ei < deg) {
        int s = bucket_src[(size_t)n * CAP + ei];
        if (hd == 0) s_lds[ei] = s;
        float _h = gd[n * HEADS + hd] + gs[s * HEADS + hd] + b_g[hd];
        float g = _h > 0.f ? _h : -P_L * _h;
        alpha_lds[ei][hd] = g * dn * dnorm[s];
    }
    __syncthreads();

    // phase 2: unrolled gather, 8 independent bf16 hh loads in flight
    int head = t >> 6;
    float acc = 0.f;
    int i = 0;
    for (; i + 8 <= deg; i += 8) {
        int s0 = s_lds[i + 0], s1 = s_lds[i + 1];
        int s2 = s_lds[i + 2], s3 = s_lds[i + 3];
        int s4 = s_lds[i + 4], s5 = s_lds[i + 5];
        int s6 = s_lds[i + 6], s7 = s_lds[i + 7];
        float h0 = __bfloat162float(hh[(size_t)s0 * HD + t]);
        float h1 = __bfloat162float(hh[(size_t)s1 * HD + t]);
        float h2 = __bfloat162float(hh[(size_t)s2 * HD + t]);
        float h3 = __bfloat162float(hh[(size_t)s3 * HD + t]);
        float h4 = __bfloat162float(hh[(size_t)s4 * HD + t]);
        float h5 = __bfloat162float(hh[(size_t)s5 * HD + t]);
        float h6 = __bfloat162float(hh[(size_t)s6 * HD + t]);
        float h7 = __bfloat162float(hh[(size_t)s7 * HD + t]);
        acc += h0 * alpha_lds[i + 0][head] + h1 * alpha_lds[i + 1][head]
             + h2 * alpha_lds[i + 2][head] + h3 * alpha_lds[i + 3][head]
             + h4 * alpha_lds[i + 4][head] + h5 * alpha_lds[i + 5][head]
             + h6 * alpha_lds[i + 6][head] + h7 * alpha_lds[i + 7][head];
    }
    for (; i < deg; ++i) {
        acc += __bfloat162float(hh[(size_t)s_lds[i] * HD + t]) * alpha_lds[i][head];
    }
    z[(size_t)n * HD + t] = acc;
}

// ---------------- overflow fixup (almost always empty) ----------------
__global__ __launch_bounds__(256) void fixup_kernel(
    const int* __restrict__ ov_list, const int* __restrict__ ov_count,
    const int* __restrict__ src, const int* __restrict__ dst,
    const float* __restrict__ dnorm, const float* __restrict__ b_g,
    const __hip_bfloat16* __restrict__ hh, const float* __restrict__ gd,
    const float* __restrict__ gs, float* __restrict__ z) {
    int cnt = *ov_count;
    if (cnt > OVCAP) cnt = OVCAP;
    int t = threadIdx.x;
    int head = t >> 6;
    for (int i = blockIdx.x; i < cnt; i += gridDim.x) {
        int e = ov_list[i];
        int s = src[e], dd = dst[e];
        float _h = gd[dd * HEADS + head] + gs[s * HEADS + head] + b_g[head];
        float g = _h > 0.f ? _h : -P_L * _h;
        float alpha = g * dnorm[dd] * dnorm[s];
        atomicAdd(&z[(size_t)dd * HD + t],
                  __bfloat162float(hh[(size_t)s * HD + t]) * alpha);
    }
}

// ---------------- output GEMM: out = z @ W_out + b_out ----------------
__global__ __launch_bounds__(256) void out_kernel(
    const float* __restrict__ z,
    const float* __restrict__ W_out, const float* __restrict__ b_out,
    float* __restrict__ out) {
    __shared__ float lw[HD][OUT_DIM];   // 64 KB
    int t = threadIdx.x;
    for (int i = t; i < HD * OUT_DIM; i += 256)
        ((float*)lw)[i] = W_out[i];
    __syncthreads();
    int j = t & 63, nl = t >> 6;
    int n = blockIdx.x * CN + nl;
    float acc = b_out[j];
    const float* zr = z + (size_t)n * HD;
    for (int k = 0; k < HD; k += 4) {
        float4 zv = *(const float4*)&zr[k];   // wave-uniform -> s_load
        acc += zv.x * lw[k][j] + zv.y * lw[k + 1][j] + zv.z * lw[k + 2][j] + zv.w * lw[k + 3][j];
    }
    out[(size_t)n * OUT_DIM + j] = acc;
}

extern "C" void kernel_launch(void* const* d_in, const int* in_sizes, int n_in,
                              void* d_out, int out_size, void* d_ws, size_t ws_size,
                              hipStream_t stream) {
    const float* h     = (const float*)d_in[0];
    const int*   src   = (const int*)d_in[1];
    const int*   dst   = (const int*)d_in[2];
    const float* dnorm = (const float*)d_in[3];
    const float* W_in  = (const float*)d_in[4];
    const float* b_in  = (const float*)d_in[5];
    const float* W_att = (const float*)d_in[6];
    const float* b_att = (const float*)d_in[7];
    const float* W_g   = (const float*)d_in[8];
    const float* b_g   = (const float*)d_in[9];
    const float* W_out = (const float*)d_in[10];
    const float* b_out = (const float*)d_in[11];
    float* out = (float*)d_out;

    char* ws = (char*)d_ws;
    __hip_bfloat16* hh = (__hip_bfloat16*)ws;            // N*256 bf16 (25.6 MB)
    ws += (size_t)N_NODES * HD * sizeof(__hip_bfloat16);
    float* z     = (float*)ws;  ws += (size_t)N_NODES * HD * sizeof(float);
    float* gd    = (float*)ws;  ws += (size_t)N_NODES * HEADS * sizeof(float);
    float* gs    = (float*)ws;  ws += (size_t)N_NODES * HEADS * sizeof(float);
    float* v_dst = (float*)ws;  ws += 256 * sizeof(float);
    float* v_src = (float*)ws;  ws += 256 * sizeof(float);
    float* c_dst = (float*)ws;  ws += 4 * sizeof(float);
    float* c_src = (float*)ws;  ws += 4 * sizeof(float);
    int* cursor     = (int*)ws; ws += (size_t)N_NODES * sizeof(int);
    int* ov_count   = (int*)ws; ws += 16;
    int* ov_list    = (int*)ws; ws += OVCAP * sizeof(int);
    int* bucket_src = (int*)ws;                          // N*CAP (12.8 MB)

    hipMemsetAsync(cursor, 0, (size_t)N_NODES * sizeof(int), stream);
    hipMemsetAsync(ov_count, 0, sizeof(int), stream);

    precompute_kernel<<<1, 256, 0, stream>>>(W_att, b_att, W_g, v_dst, v_src, c_dst, c_src);
    fill_kernel<<<(N_EDGES + 255) / 256, 256, 0, stream>>>(src, dst, cursor, bucket_src,
                                                           ov_list, ov_count);
    node_kernel<<<N_NODES / TILE_N, 256, 0, stream>>>(h, W_in, b_in, v_dst, v_src,
                                                      c_dst, c_src, hh, gd, gs);
    agg_kernel<<<N_NODES, 256, 0, stream>>>(bucket_src, cursor, dnorm, b_g,
                                            hh, gd, gs, z);
    fixup_kernel<<<16, 256, 0, stream>>>(ov_list, ov_count, src, dst, dnorm, b_g,
                                         hh, gd, gs, z);
    out_kernel<<<N_NODES / CN, 256, 0, stream>>>(z, W_out, b_out, out);
}

// Round 5
// 371.441 us; speedup vs baseline: 1.3700x; 1.3700x over previous
//
#include <hip/hip_runtime.h>
#include <hip/hip_bf16.h>

#define N_NODES 50000
#define N_EDGES 800000
#define IN_DIM 256
#define OUT_DIM 64
#define HEADS 4
#define HD 256          // HEADS*OUT_DIM
#define P_L 0.1f
#define TILE_N 16
#define CN 4
#define CAP 64          // per-node edge bucket capacity (expected max deg ~43)
#define OVCAP 4096      // overflow list capacity

typedef __attribute__((ext_vector_type(8))) short bf16x8;
typedef __attribute__((ext_vector_type(4))) float f32x4;

static __device__ __forceinline__ short f2bf(float f) {
    __hip_bfloat16 b = __float2bfloat16(f);
    return *(short*)&b;
}

// ---------------- precompute: fold W_att/b_att into W_g ----------------
__global__ __launch_bounds__(256) void precompute_kernel(
    const float* __restrict__ W_att, const float* __restrict__ b_att,
    const float* __restrict__ W_g,
    float* __restrict__ v_dst, float* __restrict__ v_src,
    float* __restrict__ c_dst, float* __restrict__ c_src) {
    int t = threadIdx.x;          // 0..255
    int h = t >> 6, dd = t & 63;
    float sd = 0.f, ss = 0.f;
    for (int e = 0; e < 64; ++e) {
        float w = W_att[h * 4096 + dd * 64 + e];
        sd += w * W_g[h * 128 + e];
        ss += w * W_g[h * 128 + 64 + e];
    }
    v_dst[t] = sd;
    v_src[t] = ss;
    if (dd == 0) {
        float cd = 0.f, cs = 0.f;
        for (int e = 0; e < 64; ++e) {
            float b = b_att[h * 64 + e];
            cd += b * W_g[h * 128 + e];
            cs += b * W_g[h * 128 + 64 + e];
        }
        c_dst[h] = cd;
        c_src[h] = cs;
    }
}

// ---------------- W_in -> bf16 transposed (W_bt[n][k]) ----------------
__global__ __launch_bounds__(256) void wconv_kernel(
    const float* __restrict__ W_in, short* __restrict__ W_bt) {
    int k = blockIdx.x, n = threadIdx.x;
    W_bt[n * 256 + k] = f2bf(W_in[k * 256 + n]);   // coalesced read, scattered 2B write (256KB total)
}

// ---------------- node transform via MFMA ----------------
// C[16 nodes][256 cols] = A[16][256] * B[256][256], bf16 inputs, f32 acc.
// wave w covers cols w*64..w*64+63 == head w.
__global__ __launch_bounds__(256) void node_mfma_kernel(
    const float* __restrict__ hin, const short* __restrict__ W_bt,
    const float* __restrict__ b_in,
    const float* __restrict__ v_dst, const float* __restrict__ v_src,
    const float* __restrict__ c_dst, const float* __restrict__ c_src,
    __hip_bfloat16* __restrict__ hh, float* __restrict__ gd,
    float* __restrict__ gs) {
    __shared__ short A_lds[16 * 256];   // 8 KB, XOR-swizzled
    int t = threadIdx.x;
    int n0 = blockIdx.x * TILE_N;

    // ---- stage A: thread t loads row r = t>>4, cols (t&15)*16 .. +15 (f32), cvt bf16
    {
        int r = t >> 4, c0 = (t & 15) * 16;
        const float* hp = hin + (size_t)(n0 + r) * IN_DIM + c0;
        float fv[16];
        *(float4*)&fv[0]  = *(const float4*)(hp + 0);
        *(float4*)&fv[4]  = *(const float4*)(hp + 4);
        *(float4*)&fv[8]  = *(const float4*)(hp + 8);
        *(float4*)&fv[12] = *(const float4*)(hp + 12);
        short sv[16];
        #pragma unroll
        for (int j = 0; j < 16; ++j) sv[j] = f2bf(fv[j]);
        int swz = (r & 7) << 3;                    // XOR in units of shorts (16B chunks)
        int base = r * 256 + c0;
        *(bf16x8*)&A_lds[(base + 0) ^ swz] = *(bf16x8*)&sv[0];
        *(bf16x8*)&A_lds[(base + 8) ^ swz] = *(bf16x8*)&sv[8];
    }
    __syncthreads();

    int l = t & 63, w = t >> 6;
    int lr = l & 15, lg = l >> 4;                  // frag row/col = lr, k-group = lg

    f32x4 acc[4];
    #pragma unroll
    for (int ct = 0; ct < 4; ++ct) acc[ct] = (f32x4){0.f, 0.f, 0.f, 0.f};

    // B pointers: col = w*64 + ct*16 + lr; frag = W_bt[col][ks*32 + lg*8 .. +7]
    const short* bp[4];
    #pragma unroll
    for (int ct = 0; ct < 4; ++ct)
        bp[ct] = W_bt + (size_t)(w * 64 + ct * 16 + lr) * 256 + lg * 8;

    int abase = lr * 256 + lg * 8;
    int aswz = (lr & 7) << 3;

    #pragma unroll
    for (int ks = 0; ks < 8; ++ks) {
        bf16x8 afrag = *(bf16x8*)&A_lds[(abase + ks * 32) ^ aswz];
        #pragma unroll
        for (int ct = 0; ct < 4; ++ct) {
            bf16x8 bfrag = *(const bf16x8*)(bp[ct] + ks * 32);
            acc[ct] = __builtin_amdgcn_mfma_f32_16x16x32_bf16(afrag, bfrag, acc[ct], 0, 0, 0);
        }
    }

    // ---- epilogue: relu(acc + b_in), store hh bf16, gd/gs reduce ----
    // D layout: col = lr, row(m) = lg*4 + r
    int col[4];
    float vd[4], vs[4], bi[4];
    #pragma unroll
    for (int ct = 0; ct < 4; ++ct) {
        col[ct] = w * 64 + ct * 16 + lr;
        bi[ct] = b_in[col[ct]];
        vd[ct] = v_dst[col[ct]];
        vs[ct] = v_src[col[ct]];
    }
    float pd[4] = {0.f, 0.f, 0.f, 0.f};
    float ps[4] = {0.f, 0.f, 0.f, 0.f};
    #pragma unroll
    for (int ct = 0; ct < 4; ++ct) {
        #pragma unroll
        for (int r = 0; r < 4; ++r) {
            float v = fmaxf(acc[ct][r] + bi[ct], 0.f);
            int m = lg * 4 + r;
            hh[(size_t)(n0 + m) * HD + col[ct]] = __float2bfloat16(v);
            pd[r] += v * vd[ct];
            ps[r] += v * vs[ct];
        }
    }
    #pragma unroll
    for (int r = 0; r < 4; ++r) {
        #pragma unroll
        for (int off = 1; off < 16; off <<= 1) {
            pd[r] += __shfl_xor(pd[r], off, 64);
            ps[r] += __shfl_xor(ps[r], off, 64);
        }
    }
    if (lr == 0) {
        float cd = c_dst[w], cs = c_src[w];
        #pragma unroll
        for (int r = 0; r < 4; ++r) {
            int m = lg * 4 + r;
            gd[(n0 + m) * HEADS + w] = pd[r] + cd;
            gs[(n0 + m) * HEADS + w] = ps[r] + cs;
        }
    }
}

// ---------------- bucket fill: group SRC node ids by dst ----------------
__global__ __launch_bounds__(256) void fill_kernel(
    const int* __restrict__ src, const int* __restrict__ dst,
    int* __restrict__ cursor, int* __restrict__ bucket_src,
    int* __restrict__ ov_list, int* __restrict__ ov_count) {
    int e = blockIdx.x * 256 + threadIdx.x;
    if (e >= N_EDGES) return;
    int n = dst[e];
    int pos = atomicAdd(&cursor[n], 1);
    if (pos < CAP) {
        bucket_src[(size_t)n * CAP + pos] = src[e];
    } else {
        int oi = atomicAdd(ov_count, 1);
        if (oi < OVCAP) ov_list[oi] = e;
    }
}

// ---------------- gather aggregation: z[n] = sum over in-edges ----------------
__global__ __launch_bounds__(256) void agg_kernel(
    const int* __restrict__ bucket_src, const int* __restrict__ cursor,
    const float* __restrict__ dnorm, const float* __restrict__ b_g,
    const __hip_bfloat16* __restrict__ hh, const float* __restrict__ gd,
    const float* __restrict__ gs, float* __restrict__ z) {
    __shared__ int s_lds[CAP];
    __shared__ float alpha_lds[CAP][HEADS];
    int n = blockIdx.x;
    int t = threadIdx.x;
    int deg = cursor[n];
    if (deg > CAP) deg = CAP;
    float dn = dnorm[n];

    // phase 1: per-edge alphas in parallel. thread t = edge (t>>2), head (t&3).
    int ei = t >> 2, hd = t & 3;
    if (ei < deg) {
        int s = bucket_src[(size_t)n * CAP + ei];
        if (hd == 0) s_lds[ei] = s;
        float _h = gd[n * HEADS + hd] + gs[s * HEADS + hd] + b_g[hd];
        float g = _h > 0.f ? _h : -P_L * _h;
        alpha_lds[ei][hd] = g * dn * dnorm[s];
    }
    __syncthreads();

    // phase 2: unrolled gather, 8 independent bf16 hh loads in flight
    int head = t >> 6;
    float acc = 0.f;
    int i = 0;
    for (; i + 8 <= deg; i += 8) {
        int s0 = s_lds[i + 0], s1 = s_lds[i + 1];
        int s2 = s_lds[i + 2], s3 = s_lds[i + 3];
        int s4 = s_lds[i + 4], s5 = s_lds[i + 5];
        int s6 = s_lds[i + 6], s7 = s_lds[i + 7];
        float h0 = __bfloat162float(hh[(size_t)s0 * HD + t]);
        float h1 = __bfloat162float(hh[(size_t)s1 * HD + t]);
        float h2 = __bfloat162float(hh[(size_t)s2 * HD + t]);
        float h3 = __bfloat162float(hh[(size_t)s3 * HD + t]);
        float h4 = __bfloat162float(hh[(size_t)s4 * HD + t]);
        float h5 = __bfloat162float(hh[(size_t)s5 * HD + t]);
        float h6 = __bfloat162float(hh[(size_t)s6 * HD + t]);
        float h7 = __bfloat162float(hh[(size_t)s7 * HD + t]);
        acc += h0 * alpha_lds[i + 0][head] + h1 * alpha_lds[i + 1][head]
             + h2 * alpha_lds[i + 2][head] + h3 * alpha_lds[i + 3][head]
             + h4 * alpha_lds[i + 4][head] + h5 * alpha_lds[i + 5][head]
             + h6 * alpha_lds[i + 6][head] + h7 * alpha_lds[i + 7][head];
    }
    for (; i < deg; ++i) {
        acc += __bfloat162float(hh[(size_t)s_lds[i] * HD + t]) * alpha_lds[i][head];
    }
    z[(size_t)n * HD + t] = acc;
}

// ---------------- overflow fixup (almost always empty) ----------------
__global__ __launch_bounds__(256) void fixup_kernel(
    const int* __restrict__ ov_list, const int* __restrict__ ov_count,
    const int* __restrict__ src, const int* __restrict__ dst,
    const float* __restrict__ dnorm, const float* __restrict__ b_g,
    const __hip_bfloat16* __restrict__ hh, const float* __restrict__ gd,
    const float* __restrict__ gs, float* __restrict__ z) {
    int cnt = *ov_count;
    if (cnt > OVCAP) cnt = OVCAP;
    int t = threadIdx.x;
    int head = t >> 6;
    for (int i = blockIdx.x; i < cnt; i += gridDim.x) {
        int e = ov_list[i];
        int s = src[e], dd = dst[e];
        float _h = gd[dd * HEADS + head] + gs[s * HEADS + head] + b_g[head];
        float g = _h > 0.f ? _h : -P_L * _h;
        float alpha = g * dnorm[dd] * dnorm[s];
        atomicAdd(&z[(size_t)dd * HD + t],
                  __bfloat162float(hh[(size_t)s * HD + t]) * alpha);
    }
}

// ---------------- output GEMM: out = z @ W_out + b_out ----------------
__global__ __launch_bounds__(256) void out_kernel(
    const float* __restrict__ z,
    const float* __restrict__ W_out, const float* __restrict__ b_out,
    float* __restrict__ out) {
    __shared__ float lw[HD][OUT_DIM];   // 64 KB
    int t = threadIdx.x;
    for (int i = t; i < HD * OUT_DIM; i += 256)
        ((float*)lw)[i] = W_out[i];
    __syncthreads();
    int j = t & 63, nl = t >> 6;
    int n = blockIdx.x * CN + nl;
    float acc = b_out[j];
    const float* zr = z + (size_t)n * HD;
    for (int k = 0; k < HD; k += 4) {
        float4 zv = *(const float4*)&zr[k];
        acc += zv.x * lw[k][j] + zv.y * lw[k + 1][j] + zv.z * lw[k + 2][j] + zv.w * lw[k + 3][j];
    }
    out[(size_t)n * OUT_DIM + j] = acc;
}

extern "C" void kernel_launch(void* const* d_in, const int* in_sizes, int n_in,
                              void* d_out, int out_size, void* d_ws, size_t ws_size,
                              hipStream_t stream) {
    const float* h     = (const float*)d_in[0];
    const int*   src   = (const int*)d_in[1];
    const int*   dst   = (const int*)d_in[2];
    const float* dnorm = (const float*)d_in[3];
    const float* W_in  = (const float*)d_in[4];
    const float* b_in  = (const float*)d_in[5];
    const float* W_att = (const float*)d_in[6];
    const float* b_att = (const float*)d_in[7];
    const float* W_g   = (const float*)d_in[8];
    const float* b_g   = (const float*)d_in[9];
    const float* W_out = (const float*)d_in[10];
    const float* b_out = (const float*)d_in[11];
    float* out = (float*)d_out;

    char* ws = (char*)d_ws;
    __hip_bfloat16* hh = (__hip_bfloat16*)ws;            // N*256 bf16 (25.6 MB)
    ws += (size_t)N_NODES * HD * sizeof(__hip_bfloat16);
    float* z     = (float*)ws;  ws += (size_t)N_NODES * HD * sizeof(float);
    float* gd    = (float*)ws;  ws += (size_t)N_NODES * HEADS * sizeof(float);
    float* gs    = (float*)ws;  ws += (size_t)N_NODES * HEADS * sizeof(float);
    float* v_dst = (float*)ws;  ws += 256 * sizeof(float);
    float* v_src = (float*)ws;  ws += 256 * sizeof(float);
    float* c_dst = (float*)ws;  ws += 4 * sizeof(float);
    float* c_src = (float*)ws;  ws += 4 * sizeof(float);
    int* cursor     = (int*)ws; ws += (size_t)N_NODES * sizeof(int);
    int* ov_count   = (int*)ws; ws += 16;
    int* ov_list    = (int*)ws; ws += OVCAP * sizeof(int);
    int* bucket_src = (int*)ws; ws += (size_t)N_NODES * CAP * sizeof(int);
    short* W_bt     = (short*)ws;                        // 256*256 bf16 (128 KB)

    hipMemsetAsync(cursor, 0, (size_t)N_NODES * sizeof(int), stream);
    hipMemsetAsync(ov_count, 0, sizeof(int), stream);

    precompute_kernel<<<1, 256, 0, stream>>>(W_att, b_att, W_g, v_dst, v_src, c_dst, c_src);
    wconv_kernel<<<256, 256, 0, stream>>>(W_in, W_bt);
    fill_kernel<<<(N_EDGES + 255) / 256, 256, 0, stream>>>(src, dst, cursor, bucket_src,
                                                           ov_list, ov_count);
    node_mfma_kernel<<<N_NODES / TILE_N, 256, 0, stream>>>(h, W_bt, b_in, v_dst, v_src,
                                                           c_dst, c_src, hh, gd, gs);
    agg_kernel<<<N_NODES, 256, 0, stream>>>(bucket_src, cursor, dnorm, b_g,
                                            hh, gd, gs, z);
    fixup_kernel<<<16, 256, 0, stream>>>(ov_list, ov_count, src, dst, dnorm, b_g,
                                         hh, gd, gs, z);
    out_kernel<<<N_NODES / CN, 256, 0, stream>>>(z, W_out, b_out, out);
}

// Round 6
// 242.714 us; speedup vs baseline: 2.0966x; 1.5304x over previous
//
#include <hip/hip_runtime.h>
#include <hip/hip_bf16.h>

#define N_NODES 50000
#define N_EDGES 800000
#define IN_DIM 256
#define OUT_DIM 64
#define HEADS 4
#define HD 256          // HEADS*OUT_DIM
#define P_L 0.1f
#define TILE_N 16
#define CAP 64          // per-node edge bucket capacity (expected max deg ~43)
#define OVCAP 4096      // overflow list capacity

typedef __attribute__((ext_vector_type(8))) short bf16x8;
typedef __attribute__((ext_vector_type(4))) float f32x4;

static __device__ __forceinline__ short f2bf(float f) {
    __hip_bfloat16 b = __float2bfloat16(f);
    return *(short*)&b;
}

// ---------------- precompute: fold W_att/b_att into W_g ----------------
__global__ __launch_bounds__(256) void precompute_kernel(
    const float* __restrict__ W_att, const float* __restrict__ b_att,
    const float* __restrict__ W_g,
    float* __restrict__ v_dst, float* __restrict__ v_src,
    float* __restrict__ c_dst, float* __restrict__ c_src) {
    int t = threadIdx.x;          // 0..255
    int h = t >> 6, dd = t & 63;
    float sd = 0.f, ss = 0.f;
    for (int e = 0; e < 64; ++e) {
        float w = W_att[h * 4096 + dd * 64 + e];
        sd += w * W_g[h * 128 + e];
        ss += w * W_g[h * 128 + 64 + e];
    }
    v_dst[t] = sd;
    v_src[t] = ss;
    if (dd == 0) {
        float cd = 0.f, cs = 0.f;
        for (int e = 0; e < 64; ++e) {
            float b = b_att[h * 64 + e];
            cd += b * W_g[h * 128 + e];
            cs += b * W_g[h * 128 + 64 + e];
        }
        c_dst[h] = cd;
        c_src[h] = cs;
    }
}

// ---- weight conversion: W_in -> W_bt[n][k] bf16; W_out -> W_obt[n][k] bf16 ----
__global__ __launch_bounds__(256) void wconv_kernel(
    const float* __restrict__ W_in, const float* __restrict__ W_out,
    short* __restrict__ W_bt, short* __restrict__ W_obt) {
    int b = blockIdx.x, t = threadIdx.x;
    if (b < 256) {
        // W_bt[n][k] = bf(W_in[k][n]); block b = row k, thread t = col n
        W_bt[t * 256 + b] = f2bf(W_in[b * 256 + t]);
    } else {
        int bb = b - 256;                 // 0..63 -> 4 k-rows each
        int k = bb * 4 + (t >> 6), n = t & 63;
        W_obt[n * 256 + k] = f2bf(W_out[k * 64 + n]);
    }
}

// ---------------- node transform via MFMA ----------------
// C[16 nodes][256 cols] = A[16][256] * B[256][256], bf16 in, f32 acc.
// wave w covers cols w*64..w*64+63 == head w.
__global__ __launch_bounds__(256) void node_mfma_kernel(
    const float* __restrict__ hin, const short* __restrict__ W_bt,
    const float* __restrict__ b_in,
    const float* __restrict__ v_dst, const float* __restrict__ v_src,
    const float* __restrict__ c_dst, const float* __restrict__ c_src,
    __hip_bfloat16* __restrict__ hh, float* __restrict__ gd,
    float* __restrict__ gs) {
    __shared__ short A_lds[16 * 256];   // 8 KB, XOR-swizzled
    int t = threadIdx.x;
    int n0 = blockIdx.x * TILE_N;

    {
        int r = t >> 4, c0 = (t & 15) * 16;
        const float* hp = hin + (size_t)(n0 + r) * IN_DIM + c0;
        float fv[16];
        *(float4*)&fv[0]  = *(const float4*)(hp + 0);
        *(float4*)&fv[4]  = *(const float4*)(hp + 4);
        *(float4*)&fv[8]  = *(const float4*)(hp + 8);
        *(float4*)&fv[12] = *(const float4*)(hp + 12);
        short sv[16];
        #pragma unroll
        for (int j = 0; j < 16; ++j) sv[j] = f2bf(fv[j]);
        int swz = (r & 7) << 3;
        int base = r * 256 + c0;
        *(bf16x8*)&A_lds[(base + 0) ^ swz] = *(bf16x8*)&sv[0];
        *(bf16x8*)&A_lds[(base + 8) ^ swz] = *(bf16x8*)&sv[8];
    }
    __syncthreads();

    int l = t & 63, w = t >> 6;
    int lr = l & 15, lg = l >> 4;

    f32x4 acc[4];
    #pragma unroll
    for (int ct = 0; ct < 4; ++ct) acc[ct] = (f32x4){0.f, 0.f, 0.f, 0.f};

    const short* bp[4];
    #pragma unroll
    for (int ct = 0; ct < 4; ++ct)
        bp[ct] = W_bt + (size_t)(w * 64 + ct * 16 + lr) * 256 + lg * 8;

    int abase = lr * 256 + lg * 8;
    int aswz = (lr & 7) << 3;

    #pragma unroll
    for (int ks = 0; ks < 8; ++ks) {
        bf16x8 afrag = *(bf16x8*)&A_lds[(abase + ks * 32) ^ aswz];
        #pragma unroll
        for (int ct = 0; ct < 4; ++ct) {
            bf16x8 bfrag = *(const bf16x8*)(bp[ct] + ks * 32);
            acc[ct] = __builtin_amdgcn_mfma_f32_16x16x32_bf16(afrag, bfrag, acc[ct], 0, 0, 0);
        }
    }

    // epilogue: relu(acc + b_in), store hh bf16, gd/gs reduce
    int col[4];
    float vd[4], vs[4], bi[4];
    #pragma unroll
    for (int ct = 0; ct < 4; ++ct) {
        col[ct] = w * 64 + ct * 16 + lr;
        bi[ct] = b_in[col[ct]];
        vd[ct] = v_dst[col[ct]];
        vs[ct] = v_src[col[ct]];
    }
    float pd[4] = {0.f, 0.f, 0.f, 0.f};
    float ps[4] = {0.f, 0.f, 0.f, 0.f};
    #pragma unroll
    for (int ct = 0; ct < 4; ++ct) {
        #pragma unroll
        for (int r = 0; r < 4; ++r) {
            float v = fmaxf(acc[ct][r] + bi[ct], 0.f);
            int m = lg * 4 + r;
            hh[(size_t)(n0 + m) * HD + col[ct]] = __float2bfloat16(v);
            pd[r] += v * vd[ct];
            ps[r] += v * vs[ct];
        }
    }
    #pragma unroll
    for (int r = 0; r < 4; ++r) {
        #pragma unroll
        for (int off = 1; off < 16; off <<= 1) {
            pd[r] += __shfl_xor(pd[r], off, 64);
            ps[r] += __shfl_xor(ps[r], off, 64);
        }
    }
    if (lr == 0) {
        float cd = c_dst[w], cs = c_src[w];
        #pragma unroll
        for (int r = 0; r < 4; ++r) {
            int m = lg * 4 + r;
            gd[(n0 + m) * HEADS + w] = pd[r] + cd;
            gs[(n0 + m) * HEADS + w] = ps[r] + cs;
        }
    }
}

// ---------------- bucket fill: group SRC node ids by dst ----------------
__global__ __launch_bounds__(256) void fill_kernel(
    const int* __restrict__ src, const int* __restrict__ dst,
    int* __restrict__ cursor, int* __restrict__ bucket_src,
    int* __restrict__ ov_list, int* __restrict__ ov_count) {
    int e = blockIdx.x * 256 + threadIdx.x;
    if (e >= N_EDGES) return;
    int n = dst[e];
    int pos = atomicAdd(&cursor[n], 1);
    if (pos < CAP) {
        bucket_src[(size_t)n * CAP + pos] = src[e];
    } else {
        int oi = atomicAdd(ov_count, 1);
        if (oi < OVCAP) ov_list[oi] = e;
    }
}

// ---------------- gather aggregation: z[n] = sum over in-edges (bf16 out) ----
__global__ __launch_bounds__(256) void agg_kernel(
    const int* __restrict__ bucket_src, const int* __restrict__ cursor,
    const int* __restrict__ src, const int* __restrict__ dst,
    const int* __restrict__ ov_list, const int* __restrict__ ov_count,
    const float* __restrict__ dnorm, const float* __restrict__ b_g,
    const __hip_bfloat16* __restrict__ hh, const float* __restrict__ gd,
    const float* __restrict__ gs, __hip_bfloat16* __restrict__ z) {
    __shared__ int s_lds[CAP];
    __shared__ float alpha_lds[CAP][HEADS];
    int n = blockIdx.x;
    int t = threadIdx.x;
    int deg = cursor[n];
    if (deg > CAP) deg = CAP;
    float dn = dnorm[n];

    // phase 1: per-edge alphas. thread t = edge (t>>2), head (t&3) — covers CAP*4=256.
    int ei = t >> 2, hd = t & 3;
    if (ei < deg) {
        int s = bucket_src[(size_t)n * CAP + ei];
        if (hd == 0) s_lds[ei] = s;
        float _h = gd[n * HEADS + hd] + gs[s * HEADS + hd] + b_g[hd];
        float g = _h > 0.f ? _h : -P_L * _h;
        alpha_lds[ei][hd] = g * dn * dnorm[s];
    }
    __syncthreads();

    // phase 2: unrolled gather, 8 independent bf16 hh loads in flight
    int head = t >> 6;
    float acc = 0.f;
    int i = 0;
    for (; i + 8 <= deg; i += 8) {
        int s0 = s_lds[i + 0], s1 = s_lds[i + 1];
        int s2 = s_lds[i + 2], s3 = s_lds[i + 3];
        int s4 = s_lds[i + 4], s5 = s_lds[i + 5];
        int s6 = s_lds[i + 6], s7 = s_lds[i + 7];
        float h0 = __bfloat162float(hh[(size_t)s0 * HD + t]);
        float h1 = __bfloat162float(hh[(size_t)s1 * HD + t]);
        float h2 = __bfloat162float(hh[(size_t)s2 * HD + t]);
        float h3 = __bfloat162float(hh[(size_t)s3 * HD + t]);
        float h4 = __bfloat162float(hh[(size_t)s4 * HD + t]);
        float h5 = __bfloat162float(hh[(size_t)s5 * HD + t]);
        float h6 = __bfloat162float(hh[(size_t)s6 * HD + t]);
        float h7 = __bfloat162float(hh[(size_t)s7 * HD + t]);
        acc += h0 * alpha_lds[i + 0][head] + h1 * alpha_lds[i + 1][head]
             + h2 * alpha_lds[i + 2][head] + h3 * alpha_lds[i + 3][head]
             + h4 * alpha_lds[i + 4][head] + h5 * alpha_lds[i + 5][head]
             + h6 * alpha_lds[i + 6][head] + h7 * alpha_lds[i + 7][head];
    }
    for (; i < deg; ++i) {
        acc += __bfloat162float(hh[(size_t)s_lds[i] * HD + t]) * alpha_lds[i][head];
    }

    // overflow edges (cnt is ~always 0; uniform branch, broadcast loads)
    int cnt = *ov_count;
    if (cnt > 0) {
        if (cnt > OVCAP) cnt = OVCAP;
        for (int j = 0; j < cnt; ++j) {
            int e = ov_list[j];
            if (dst[e] == n) {
                int s = src[e];
                float _h = gd[n * HEADS + head] + gs[s * HEADS + head] + b_g[head];
                float g = _h > 0.f ? _h : -P_L * _h;
                float alpha = g * dn * dnorm[s];
                acc += __bfloat162float(hh[(size_t)s * HD + t]) * alpha;
            }
        }
    }
    z[(size_t)n * HD + t] = __float2bfloat16(acc);
}

// ---------------- output GEMM via MFMA: out = z @ W_out + b_out --------------
// block = 64 nodes, 4 waves; wave wv -> nodes n0+wv*16..+15, all 64 cols.
__global__ __launch_bounds__(256) void out_mfma_kernel(
    const __hip_bfloat16* __restrict__ z, const short* __restrict__ W_obt,
    const float* __restrict__ b_out, float* __restrict__ out) {
    __shared__ short A_lds[64 * 256];   // 32 KB, XOR-swizzled
    int t = threadIdx.x;
    int n0 = blockIdx.x * 64;

    {
        int r = t >> 2, c0 = (t & 3) * 64;
        const short* zp = (const short*)z + (size_t)(n0 + r) * HD + c0;  // OOB rows read ws garbage: never stored
        int swz = (r & 7) << 3;
        int base = r * 256 + c0;
        #pragma unroll
        for (int j = 0; j < 8; ++j) {
            bf16x8 v = *(const bf16x8*)(zp + j * 8);
            *(bf16x8*)&A_lds[(base + j * 8) ^ swz] = v;
        }
    }
    __syncthreads();

    int l = t & 63, wv = t >> 6;
    int lr = l & 15, lg = l >> 4;

    f32x4 acc[4];
    #pragma unroll
    for (int ct = 0; ct < 4; ++ct) acc[ct] = (f32x4){0.f, 0.f, 0.f, 0.f};

    const short* bp[4];
    #pragma unroll
    for (int ct = 0; ct < 4; ++ct)
        bp[ct] = W_obt + (size_t)(ct * 16 + lr) * 256 + lg * 8;

    int arow = wv * 16 + lr;
    int abase = arow * 256 + lg * 8;
    int aswz = (lr & 7) << 3;      // arow&7 == lr&7

    #pragma unroll
    for (int ks = 0; ks < 8; ++ks) {
        bf16x8 afrag = *(bf16x8*)&A_lds[(abase + ks * 32) ^ aswz];
        #pragma unroll
        for (int ct = 0; ct < 4; ++ct) {
            bf16x8 bfrag = *(const bf16x8*)(bp[ct] + ks * 32);
            acc[ct] = __builtin_amdgcn_mfma_f32_16x16x32_bf16(afrag, bfrag, acc[ct], 0, 0, 0);
        }
    }

    #pragma unroll
    for (int ct = 0; ct < 4; ++ct) {
        float bo = b_out[ct * 16 + lr];
        #pragma unroll
        for (int r = 0; r < 4; ++r) {
            int m = n0 + wv * 16 + lg * 4 + r;
            if (m < N_NODES)
                out[(size_t)m * OUT_DIM + ct * 16 + lr] = acc[ct][r] + bo;
        }
    }
}

extern "C" void kernel_launch(void* const* d_in, const int* in_sizes, int n_in,
                              void* d_out, int out_size, void* d_ws, size_t ws_size,
                              hipStream_t stream) {
    const float* h     = (const float*)d_in[0];
    const int*   src   = (const int*)d_in[1];
    const int*   dst   = (const int*)d_in[2];
    const float* dnorm = (const float*)d_in[3];
    const float* W_in  = (const float*)d_in[4];
    const float* b_in  = (const float*)d_in[5];
    const float* W_att = (const float*)d_in[6];
    const float* b_att = (const float*)d_in[7];
    const float* W_g   = (const float*)d_in[8];
    const float* b_g   = (const float*)d_in[9];
    const float* W_out = (const float*)d_in[10];
    const float* b_out = (const float*)d_in[11];
    float* out = (float*)d_out;

    char* ws = (char*)d_ws;
    __hip_bfloat16* hh = (__hip_bfloat16*)ws;            // N*256 bf16 (25.6 MB)
    ws += (size_t)N_NODES * HD * sizeof(__hip_bfloat16);
    __hip_bfloat16* z = (__hip_bfloat16*)ws;             // N*256 bf16 (25.6 MB)
    ws += (size_t)N_NODES * HD * sizeof(__hip_bfloat16);
    float* gd    = (float*)ws;  ws += (size_t)N_NODES * HEADS * sizeof(float);
    float* gs    = (float*)ws;  ws += (size_t)N_NODES * HEADS * sizeof(float);
    float* v_dst = (float*)ws;  ws += 256 * sizeof(float);
    float* v_src = (float*)ws;  ws += 256 * sizeof(float);
    float* c_dst = (float*)ws;  ws += 16;
    float* c_src = (float*)ws;  ws += 16;
    int* cursor     = (int*)ws; ws += (size_t)N_NODES * sizeof(int);
    int* ov_count   = (int*)ws; ws += 16;
    int* ov_list    = (int*)ws; ws += OVCAP * sizeof(int);
    int* bucket_src = (int*)ws; ws += (size_t)N_NODES * CAP * sizeof(int);
    short* W_bt     = (short*)ws; ws += 256 * 256 * sizeof(short);   // 128 KB
    short* W_obt    = (short*)ws;                                    // 64*256 bf16 (32 KB)

    hipMemsetAsync(cursor, 0, (size_t)N_NODES * sizeof(int), stream);
    hipMemsetAsync(ov_count, 0, sizeof(int), stream);

    precompute_kernel<<<1, 256, 0, stream>>>(W_att, b_att, W_g, v_dst, v_src, c_dst, c_src);
    wconv_kernel<<<320, 256, 0, stream>>>(W_in, W_out, W_bt, W_obt);
    fill_kernel<<<(N_EDGES + 255) / 256, 256, 0, stream>>>(src, dst, cursor, bucket_src,
                                                           ov_list, ov_count);
    node_mfma_kernel<<<N_NODES / TILE_N, 256, 0, stream>>>(h, W_bt, b_in, v_dst, v_src,
                                                           c_dst, c_src, hh, gd, gs);
    agg_kernel<<<N_NODES, 256, 0, stream>>>(bucket_src, cursor, src, dst, ov_list, ov_count,
                                            dnorm, b_g, hh, gd, gs, z);
    out_mfma_kernel<<<(N_NODES + 63) / 64, 256, 0, stream>>>(z, W_obt, b_out, out);
}

// Round 7
// 196.427 us; speedup vs baseline: 2.5907x; 1.2356x over previous
//
#include <hip/hip_runtime.h>
#include <hip/hip_bf16.h>

#define N_NODES 50000
#define N_EDGES 800000
#define IN_DIM 256
#define OUT_DIM 64
#define HEADS 4
#define HD 256          // HEADS*OUT_DIM
#define P_L 0.1f
#define TILE_N 16
#define CAP 64          // per-node edge bucket capacity (expected max deg ~43)
#define OVCAP 4096      // overflow list capacity

typedef __attribute__((ext_vector_type(8))) short bf16x8;
typedef __attribute__((ext_vector_type(4))) float f32x4;

static __device__ __forceinline__ short f2bf(float f) {
    __hip_bfloat16 b = __float2bfloat16(f);
    return *(short*)&b;
}

// ---------------- precompute: fold W_att/b_att into W_g ----------------
__global__ __launch_bounds__(256) void precompute_kernel(
    const float* __restrict__ W_att, const float* __restrict__ b_att,
    const float* __restrict__ W_g,
    float* __restrict__ v_dst, float* __restrict__ v_src,
    float* __restrict__ c_dst, float* __restrict__ c_src) {
    int t = threadIdx.x;          // 0..255
    int h = t >> 6, dd = t & 63;
    float sd = 0.f, ss = 0.f;
    for (int e = 0; e < 64; ++e) {
        float w = W_att[h * 4096 + dd * 64 + e];
        sd += w * W_g[h * 128 + e];
        ss += w * W_g[h * 128 + 64 + e];
    }
    v_dst[t] = sd;
    v_src[t] = ss;
    if (dd == 0) {
        float cd = 0.f, cs = 0.f;
        for (int e = 0; e < 64; ++e) {
            float b = b_att[h * 64 + e];
            cd += b * W_g[h * 128 + e];
            cs += b * W_g[h * 128 + 64 + e];
        }
        c_dst[h] = cd;
        c_src[h] = cs;
    }
}

// ---- weight conversion ----
// W_bt[n][k]  = bf(W_in[k][n])                      (256x256)
// W_obt2[(h*64+oc)][k] = bf(W_out[h*64+k][oc])      (256x64, per-head B^T)
__global__ __launch_bounds__(256) void wconv_kernel(
    const float* __restrict__ W_in, const float* __restrict__ W_out,
    short* __restrict__ W_bt, short* __restrict__ W_obt2) {
    int b = blockIdx.x, t = threadIdx.x;
    if (b < 256) {
        W_bt[t * 256 + b] = f2bf(W_in[b * 256 + t]);
    } else {
        int flat = (b - 256) * 256 + t;        // [0, 16384)
        int k = flat & 63, oc = (flat >> 6) & 63, h = flat >> 12;
        W_obt2[flat] = f2bf(W_out[(h * 64 + k) * 64 + oc]);
    }
}

// ---------------- node transform via MFMA (+ fused out-projection y) --------
// hh[16x256] = relu(A[16x256] @ W_in + b); gd/gs reduced per head;
// y[16 nodes][h*64+oc] = hh[:, h*64: h*64+64] @ W_out[h-block]  (bf16 out)
__global__ __launch_bounds__(256) void node_mfma_kernel(
    const float* __restrict__ hin, const short* __restrict__ W_bt,
    const short* __restrict__ W_obt2, const float* __restrict__ b_in,
    const float* __restrict__ v_dst, const float* __restrict__ v_src,
    const float* __restrict__ c_dst, const float* __restrict__ c_src,
    __hip_bfloat16* __restrict__ y, float* __restrict__ gd,
    float* __restrict__ gs) {
    __shared__ short A_lds[16 * 256];   // 8 KB, XOR-swizzled
    int t = threadIdx.x;
    int n0 = blockIdx.x * TILE_N;

    {   // stage input h tile
        int r = t >> 4, c0 = (t & 15) * 16;
        const float* hp = hin + (size_t)(n0 + r) * IN_DIM + c0;
        float fv[16];
        *(float4*)&fv[0]  = *(const float4*)(hp + 0);
        *(float4*)&fv[4]  = *(const float4*)(hp + 4);
        *(float4*)&fv[8]  = *(const float4*)(hp + 8);
        *(float4*)&fv[12] = *(const float4*)(hp + 12);
        short sv[16];
        #pragma unroll
        for (int j = 0; j < 16; ++j) sv[j] = f2bf(fv[j]);
        int swz = (r & 7) << 3;
        int base = r * 256 + c0;
        *(bf16x8*)&A_lds[(base + 0) ^ swz] = *(bf16x8*)&sv[0];
        *(bf16x8*)&A_lds[(base + 8) ^ swz] = *(bf16x8*)&sv[8];
    }
    __syncthreads();

    int l = t & 63, w = t >> 6;
    int lr = l & 15, lg = l >> 4;

    f32x4 acc[4];
    #pragma unroll
    for (int ct = 0; ct < 4; ++ct) acc[ct] = (f32x4){0.f, 0.f, 0.f, 0.f};

    const short* bp[4];
    #pragma unroll
    for (int ct = 0; ct < 4; ++ct)
        bp[ct] = W_bt + (size_t)(w * 64 + ct * 16 + lr) * 256 + lg * 8;

    int abase = lr * 256 + lg * 8;
    int aswz = (lr & 7) << 3;

    #pragma unroll
    for (int ks = 0; ks < 8; ++ks) {
        bf16x8 afrag = *(bf16x8*)&A_lds[(abase + ks * 32) ^ aswz];
        #pragma unroll
        for (int ct = 0; ct < 4; ++ct) {
            bf16x8 bfrag = *(const bf16x8*)(bp[ct] + ks * 32);
            acc[ct] = __builtin_amdgcn_mfma_f32_16x16x32_bf16(afrag, bfrag, acc[ct], 0, 0, 0);
        }
    }

    // epilogue: hv = relu(acc + b_in); gd/gs reduce (C layout: col=lr, row=lg*4+r)
    int col[4];
    float vd[4], vs[4], bi[4];
    #pragma unroll
    for (int ct = 0; ct < 4; ++ct) {
        col[ct] = w * 64 + ct * 16 + lr;
        bi[ct] = b_in[col[ct]];
        vd[ct] = v_dst[col[ct]];
        vs[ct] = v_src[col[ct]];
    }
    float hv[4][4];
    float pd[4] = {0.f, 0.f, 0.f, 0.f};
    float ps[4] = {0.f, 0.f, 0.f, 0.f};
    #pragma unroll
    for (int ct = 0; ct < 4; ++ct) {
        #pragma unroll
        for (int r = 0; r < 4; ++r) {
            float v = fmaxf(acc[ct][r] + bi[ct], 0.f);
            hv[ct][r] = v;
            pd[r] += v * vd[ct];
            ps[r] += v * vs[ct];
        }
    }
    #pragma unroll
    for (int r = 0; r < 4; ++r) {
        #pragma unroll
        for (int off = 1; off < 16; off <<= 1) {
            pd[r] += __shfl_xor(pd[r], off, 64);
            ps[r] += __shfl_xor(ps[r], off, 64);
        }
    }
    if (lr == 0) {
        float cd = c_dst[w], cs = c_src[w];
        #pragma unroll
        for (int r = 0; r < 4; ++r) {
            int m = lg * 4 + r;
            gd[(n0 + m) * HEADS + w] = pd[r] + cd;
            gs[(n0 + m) * HEADS + w] = ps[r] + cs;
        }
    }

    // restage hh into A_lds (each wave owns its head's 64-col stripe)
    __syncthreads();   // all waves done reading input-h
    #pragma unroll
    for (int ct = 0; ct < 4; ++ct) {
        #pragma unroll
        for (int r = 0; r < 4; ++r) {
            int m = lg * 4 + r;
            int idx = m * 256 + col[ct];
            A_lds[idx ^ ((m & 7) << 3)] = f2bf(hv[ct][r]);
        }
    }
    __syncthreads();

    // y-GEMM: per head h=w, [16 nodes x 64k] @ [64k x 64oc]
    f32x4 acc2[4];
    #pragma unroll
    for (int ct = 0; ct < 4; ++ct) acc2[ct] = (f32x4){0.f, 0.f, 0.f, 0.f};
    const short* bp2[4];
    #pragma unroll
    for (int ct = 0; ct < 4; ++ct)
        bp2[ct] = W_obt2 + (size_t)(w * 64 + ct * 16 + lr) * 64 + lg * 8;
    int abase2 = lr * 256 + w * 64 + lg * 8;
    #pragma unroll
    for (int ks = 0; ks < 2; ++ks) {
        bf16x8 afrag = *(bf16x8*)&A_lds[(abase2 + ks * 32) ^ aswz];
        #pragma unroll
        for (int ct = 0; ct < 4; ++ct) {
            bf16x8 bfrag = *(const bf16x8*)(bp2[ct] + ks * 32);
            acc2[ct] = __builtin_amdgcn_mfma_f32_16x16x32_bf16(afrag, bfrag, acc2[ct], 0, 0, 0);
        }
    }
    #pragma unroll
    for (int ct = 0; ct < 4; ++ct) {
        #pragma unroll
        for (int r = 0; r < 4; ++r) {
            int m = lg * 4 + r;
            y[(size_t)(n0 + m) * HD + w * 64 + ct * 16 + lr] =
                __float2bfloat16(acc2[ct][r]);
        }
    }
}

// ---------------- bucket fill: group SRC node ids by dst ----------------
__global__ __launch_bounds__(256) void fill_kernel(
    const int* __restrict__ src, const int* __restrict__ dst,
    int* __restrict__ cursor, int* __restrict__ bucket_src,
    int* __restrict__ ov_list, int* __restrict__ ov_count) {
    int e = blockIdx.x * 256 + threadIdx.x;
    if (e >= N_EDGES) return;
    int n = dst[e];
    int pos = atomicAdd(&cursor[n], 1);
    if (pos < CAP) {
        bucket_src[(size_t)n * CAP + pos] = src[e];
    } else {
        int oi = atomicAdd(ov_count, 1);
        if (oi < OVCAP) ov_list[oi] = e;
    }
}

// -------- gather aggregation, wave-per-node: out[n] = b_out + sum alpha*y ----
__global__ __launch_bounds__(256) void agg_kernel(
    const int* __restrict__ bucket_src, const int* __restrict__ cursor,
    const int* __restrict__ src, const int* __restrict__ dst,
    const int* __restrict__ ov_list, const int* __restrict__ ov_count,
    const float* __restrict__ dnorm, const float* __restrict__ b_g,
    const __hip_bfloat16* __restrict__ y, const float* __restrict__ gd,
    const float* __restrict__ gs, const float* __restrict__ b_out,
    float* __restrict__ out) {
    __shared__ float alpha_lds[4][CAP][HEADS];   // 4 KB
    __shared__ int s_lds[4][CAP];                // 1 KB
    int t = threadIdx.x;
    int wv = t >> 6, lane = t & 63;
    int n = blockIdx.x * 4 + wv;
    int deg = cursor[n];
    if (deg > CAP) deg = CAP;
    float dn = dnorm[n];

    // phase 1: per-edge alphas; lane = (edge & 15)*4 + head, 16 edges/iter
    int hd = lane & 3;
    float gdh = gd[n * HEADS + hd] + b_g[hd];
    #pragma unroll
    for (int it = 0; it < 4; ++it) {
        int ei = it * 16 + (lane >> 2);
        if (ei < deg) {
            int s = bucket_src[(size_t)n * CAP + ei];
            if (hd == 0) s_lds[wv][ei] = s;
            float _h = gdh + gs[s * HEADS + hd];
            float g = _h > 0.f ? _h : -P_L * _h;
            alpha_lds[wv][ei][hd] = g * dn * dnorm[s];
        }
    }
    __syncthreads();

    // phase 2: lane covers flattened cols lane*4..+3 (head = lane>>4)
    int h_l = lane >> 4;
    const unsigned int* yw = (const unsigned int*)y + lane * 2;
    float a0 = 0.f, a1 = 0.f, a2 = 0.f, a3 = 0.f;
    int i = 0;
    for (; i + 8 <= deg; i += 8) {
        uint2 v[8];
        float al[8];
        #pragma unroll
        for (int j = 0; j < 8; ++j) {
            int s = s_lds[wv][i + j];
            al[j] = alpha_lds[wv][i + j][h_l];
            v[j] = *(const uint2*)(yw + (size_t)s * 128);
        }
        #pragma unroll
        for (int j = 0; j < 8; ++j) {
            a0 += __uint_as_float(v[j].x << 16) * al[j];
            a1 += __uint_as_float(v[j].x & 0xffff0000u) * al[j];
            a2 += __uint_as_float(v[j].y << 16) * al[j];
            a3 += __uint_as_float(v[j].y & 0xffff0000u) * al[j];
        }
    }
    for (; i < deg; ++i) {
        int s = s_lds[wv][i];
        float al = alpha_lds[wv][i][h_l];
        uint2 vv = *(const uint2*)(yw + (size_t)s * 128);
        a0 += __uint_as_float(vv.x << 16) * al;
        a1 += __uint_as_float(vv.x & 0xffff0000u) * al;
        a2 += __uint_as_float(vv.y << 16) * al;
        a3 += __uint_as_float(vv.y & 0xffff0000u) * al;
    }

    // overflow edges (cnt ~always 0; uniform per-wave branch)
    int cnt = *ov_count;
    if (cnt > 0) {
        if (cnt > OVCAP) cnt = OVCAP;
        float gdh2 = gd[n * HEADS + h_l] + b_g[h_l];
        for (int j = 0; j < cnt; ++j) {
            int e = ov_list[j];
            if (dst[e] == n) {
                int s = src[e];
                float _h = gdh2 + gs[s * HEADS + h_l];
                float g = _h > 0.f ? _h : -P_L * _h;
                float al = g * dn * dnorm[s];
                uint2 vv = *(const uint2*)(yw + (size_t)s * 128);
                a0 += __uint_as_float(vv.x << 16) * al;
                a1 += __uint_as_float(vv.x & 0xffff0000u) * al;
                a2 += __uint_as_float(vv.y << 16) * al;
                a3 += __uint_as_float(vv.y & 0xffff0000u) * al;
            }
        }
    }

    // reduce over heads (lanes l, l^16, l^32, l^48 share oc) and store
    a0 += __shfl_xor(a0, 16, 64); a0 += __shfl_xor(a0, 32, 64);
    a1 += __shfl_xor(a1, 16, 64); a1 += __shfl_xor(a1, 32, 64);
    a2 += __shfl_xor(a2, 16, 64); a2 += __shfl_xor(a2, 32, 64);
    a3 += __shfl_xor(a3, 16, 64); a3 += __shfl_xor(a3, 32, 64);
    if (lane < 16) {
        float4 bo = *(const float4*)&b_out[lane * 4];
        float4 o;
        o.x = a0 + bo.x; o.y = a1 + bo.y; o.z = a2 + bo.z; o.w = a3 + bo.w;
        *(float4*)&out[(size_t)n * OUT_DIM + lane * 4] = o;
    }
}

extern "C" void kernel_launch(void* const* d_in, const int* in_sizes, int n_in,
                              void* d_out, int out_size, void* d_ws, size_t ws_size,
                              hipStream_t stream) {
    const float* h     = (const float*)d_in[0];
    const int*   src   = (const int*)d_in[1];
    const int*   dst   = (const int*)d_in[2];
    const float* dnorm = (const float*)d_in[3];
    const float* W_in  = (const float*)d_in[4];
    const float* b_in  = (const float*)d_in[5];
    const float* W_att = (const float*)d_in[6];
    const float* b_att = (const float*)d_in[7];
    const float* W_g   = (const float*)d_in[8];
    const float* b_g   = (const float*)d_in[9];
    const float* W_out = (const float*)d_in[10];
    const float* b_out = (const float*)d_in[11];
    float* out = (float*)d_out;

    char* ws = (char*)d_ws;
    __hip_bfloat16* y = (__hip_bfloat16*)ws;             // N*256 bf16 (25.6 MB)
    ws += (size_t)N_NODES * HD * sizeof(__hip_bfloat16);
    float* gd    = (float*)ws;  ws += (size_t)N_NODES * HEADS * sizeof(float);
    float* gs    = (float*)ws;  ws += (size_t)N_NODES * HEADS * sizeof(float);
    float* v_dst = (float*)ws;  ws += 256 * sizeof(float);
    float* v_src = (float*)ws;  ws += 256 * sizeof(float);
    float* c_dst = (float*)ws;  ws += 16;
    float* c_src = (float*)ws;  ws += 16;
    int* cursor     = (int*)ws; ws += (size_t)N_NODES * sizeof(int);
    int* ov_count   = (int*)ws; ws += 16;
    int* ov_list    = (int*)ws; ws += OVCAP * sizeof(int);
    int* bucket_src = (int*)ws; ws += (size_t)N_NODES * CAP * sizeof(int);
    short* W_bt     = (short*)ws; ws += 256 * 256 * sizeof(short);   // 128 KB
    short* W_obt2   = (short*)ws;                                    // 32 KB

    hipMemsetAsync(cursor, 0, (size_t)N_NODES * sizeof(int), stream);
    hipMemsetAsync(ov_count, 0, sizeof(int), stream);

    precompute_kernel<<<1, 256, 0, stream>>>(W_att, b_att, W_g, v_dst, v_src, c_dst, c_src);
    wconv_kernel<<<320, 256, 0, stream>>>(W_in, W_out, W_bt, W_obt2);
    fill_kernel<<<(N_EDGES + 255) / 256, 256, 0, stream>>>(src, dst, cursor, bucket_src,
                                                           ov_list, ov_count);
    node_mfma_kernel<<<N_NODES / TILE_N, 256, 0, stream>>>(h, W_bt, W_obt2, b_in,
                                                           v_dst, v_src, c_dst, c_src,
                                                           y, gd, gs);
    agg_kernel<<<N_NODES / 4, 256, 0, stream>>>(bucket_src, cursor, src, dst,
                                                ov_list, ov_count, dnorm, b_g,
                                                y, gd, gs, b_out, out);
}

// Round 8
// 183.227 us; speedup vs baseline: 2.7773x; 1.0720x over previous
//
#include <hip/hip_runtime.h>
#include <hip/hip_bf16.h>

#define N_NODES 50000
#define N_EDGES 800000
#define IN_DIM 256
#define OUT_DIM 64
#define HEADS 4
#define HD 256          // HEADS*OUT_DIM
#define P_L 0.1f
#define TILE_N 64       // nodes per block (4 row-tiles of 16)
#define CAP 64          // per-node edge bucket capacity (expected max deg ~43)
#define OVCAP 4096      // overflow list capacity

typedef __attribute__((ext_vector_type(8))) short bf16x8;
typedef __attribute__((ext_vector_type(4))) float f32x4;

static __device__ __forceinline__ short f2bf(float f) {
    __hip_bfloat16 b = __float2bfloat16(f);
    return *(short*)&b;
}

// ---------------- precompute: fold W_att/b_att into W_g ----------------
__global__ __launch_bounds__(256) void precompute_kernel(
    const float* __restrict__ W_att, const float* __restrict__ b_att,
    const float* __restrict__ W_g,
    float* __restrict__ v_dst, float* __restrict__ v_src,
    float* __restrict__ c_dst, float* __restrict__ c_src) {
    int t = threadIdx.x;          // 0..255
    int h = t >> 6, dd = t & 63;
    float sd = 0.f, ss = 0.f;
    for (int e = 0; e < 64; ++e) {
        float w = W_att[h * 4096 + dd * 64 + e];
        sd += w * W_g[h * 128 + e];
        ss += w * W_g[h * 128 + 64 + e];
    }
    v_dst[t] = sd;
    v_src[t] = ss;
    if (dd == 0) {
        float cd = 0.f, cs = 0.f;
        for (int e = 0; e < 64; ++e) {
            float b = b_att[h * 64 + e];
            cd += b * W_g[h * 128 + e];
            cs += b * W_g[h * 128 + 64 + e];
        }
        c_dst[h] = cd;
        c_src[h] = cs;
    }
}

// ---- weight conversion ----
// W_bt[n][k]  = bf(W_in[k][n])                      (256x256)
// W_obt2[(h*64+oc)][k] = bf(W_out[h*64+k][oc])      (256x64, per-head B^T)
__global__ __launch_bounds__(256) void wconv_kernel(
    const float* __restrict__ W_in, const float* __restrict__ W_out,
    short* __restrict__ W_bt, short* __restrict__ W_obt2) {
    int b = blockIdx.x, t = threadIdx.x;
    if (b < 256) {
        W_bt[t * 256 + b] = f2bf(W_in[b * 256 + t]);
    } else {
        int flat = (b - 256) * 256 + t;        // [0, 16384)
        int k = flat & 63, oc = (flat >> 6) & 63, h = flat >> 12;
        W_obt2[flat] = f2bf(W_out[(h * 64 + k) * 64 + oc]);
    }
}

// ---------------- node transform via MFMA (+ fused out-projection y) --------
// 64 nodes/block. hh = relu(h@W_in+b); gd/gs per head; y = per-head hh@W_out.
__global__ __launch_bounds__(256, 2) void node_mfma_kernel(
    const float* __restrict__ hin, const short* __restrict__ W_bt,
    const short* __restrict__ W_obt2, const float* __restrict__ b_in,
    const float* __restrict__ v_dst, const float* __restrict__ v_src,
    const float* __restrict__ c_dst, const float* __restrict__ c_src,
    __hip_bfloat16* __restrict__ y, float* __restrict__ gd,
    float* __restrict__ gs) {
    __shared__ short A_lds[TILE_N * 256];   // 32 KB, XOR-swizzled
    int t = threadIdx.x;
    int n0 = blockIdx.x * TILE_N;
    bool full = (n0 + TILE_N) <= N_NODES;

    // ---- stage h tile (4 passes of the 16-row pattern) ----
    #pragma unroll
    for (int rr = 0; rr < 4; ++rr) {
        int r = rr * 16 + (t >> 4), c0 = (t & 15) * 16;
        int row = n0 + r;
        if (row > N_NODES - 1) row = N_NODES - 1;   // clamp (tail block)
        const float* hp = hin + (size_t)row * IN_DIM + c0;
        float fv[16];
        *(float4*)&fv[0]  = *(const float4*)(hp + 0);
        *(float4*)&fv[4]  = *(const float4*)(hp + 4);
        *(float4*)&fv[8]  = *(const float4*)(hp + 8);
        *(float4*)&fv[12] = *(const float4*)(hp + 12);
        short sv[16];
        #pragma unroll
        for (int j = 0; j < 16; ++j) sv[j] = f2bf(fv[j]);
        int swz = (r & 7) << 3;
        int base = r * 256 + c0;
        *(bf16x8*)&A_lds[(base + 0) ^ swz] = *(bf16x8*)&sv[0];
        *(bf16x8*)&A_lds[(base + 8) ^ swz] = *(bf16x8*)&sv[8];
    }
    __syncthreads();

    int l = t & 63, w = t >> 6;
    int lr = l & 15, lg = l >> 4;
    int aswz = (lr & 7) << 3;

    f32x4 acc[4][4];   // [row-tile][col-tile]
    #pragma unroll
    for (int rt = 0; rt < 4; ++rt)
        #pragma unroll
        for (int ct = 0; ct < 4; ++ct) acc[rt][ct] = (f32x4){0.f, 0.f, 0.f, 0.f};

    #pragma unroll
    for (int ks = 0; ks < 8; ++ks) {
        bf16x8 bfrag[4], afrag[4];
        #pragma unroll
        for (int ct = 0; ct < 4; ++ct)
            bfrag[ct] = *(const bf16x8*)(W_bt + (size_t)(w * 64 + ct * 16 + lr) * 256 + ks * 32 + lg * 8);
        #pragma unroll
        for (int rt = 0; rt < 4; ++rt)
            afrag[rt] = *(bf16x8*)&A_lds[((rt * 16 + lr) * 256 + ks * 32 + lg * 8) ^ aswz];
        #pragma unroll
        for (int rt = 0; rt < 4; ++rt)
            #pragma unroll
            for (int ct = 0; ct < 4; ++ct)
                acc[rt][ct] = __builtin_amdgcn_mfma_f32_16x16x32_bf16(afrag[rt], bfrag[ct], acc[rt][ct], 0, 0, 0);
    }

    // ---- epilogue: relu(+b_in) in place, gd/gs partials ----
    int col[4];
    float vd[4], vs[4], bi[4];
    #pragma unroll
    for (int ct = 0; ct < 4; ++ct) {
        col[ct] = w * 64 + ct * 16 + lr;
        bi[ct] = b_in[col[ct]];
        vd[ct] = v_dst[col[ct]];
        vs[ct] = v_src[col[ct]];
    }
    float pd[4][4], ps[4][4];   // [rt][r]
    #pragma unroll
    for (int rt = 0; rt < 4; ++rt)
        #pragma unroll
        for (int r = 0; r < 4; ++r) { pd[rt][r] = 0.f; ps[rt][r] = 0.f; }
    #pragma unroll
    for (int rt = 0; rt < 4; ++rt)
        #pragma unroll
        for (int ct = 0; ct < 4; ++ct)
            #pragma unroll
            for (int r = 0; r < 4; ++r) {
                float v = fmaxf(acc[rt][ct][r] + bi[ct], 0.f);
                acc[rt][ct][r] = v;          // reuse as hh value
                pd[rt][r] += v * vd[ct];
                ps[rt][r] += v * vs[ct];
            }
    #pragma unroll
    for (int rt = 0; rt < 4; ++rt)
        #pragma unroll
        for (int r = 0; r < 4; ++r) {
            #pragma unroll
            for (int off = 1; off < 16; off <<= 1) {
                pd[rt][r] += __shfl_xor(pd[rt][r], off, 64);
                ps[rt][r] += __shfl_xor(ps[rt][r], off, 64);
            }
        }
    if (lr == 0) {
        float cd = c_dst[w], cs = c_src[w];
        #pragma unroll
        for (int rt = 0; rt < 4; ++rt)
            #pragma unroll
            for (int r = 0; r < 4; ++r) {
                int m = rt * 16 + lg * 4 + r;
                if (full || (n0 + m) < N_NODES) {
                    gd[(n0 + m) * HEADS + w] = pd[rt][r] + cd;
                    gs[(n0 + m) * HEADS + w] = ps[rt][r] + cs;
                }
            }
    }

    // ---- restage hh into A_lds for the y-GEMM ----
    __syncthreads();   // everyone done reading input-h tile
    #pragma unroll
    for (int rt = 0; rt < 4; ++rt)
        #pragma unroll
        for (int ct = 0; ct < 4; ++ct)
            #pragma unroll
            for (int r = 0; r < 4; ++r) {
                int m = rt * 16 + lg * 4 + r;
                int idx = m * 256 + col[ct];
                A_lds[idx ^ (((lg * 4 + r) & 7) << 3)] = f2bf(acc[rt][ct][r]);
            }
    __syncthreads();

    // ---- y-GEMM: per head w, [64 nodes x 64k] @ [64k x 64oc] ----
    f32x4 acc2[4][4];
    #pragma unroll
    for (int rt = 0; rt < 4; ++rt)
        #pragma unroll
        for (int ct = 0; ct < 4; ++ct) acc2[rt][ct] = (f32x4){0.f, 0.f, 0.f, 0.f};
    #pragma unroll
    for (int ks = 0; ks < 2; ++ks) {
        bf16x8 bfrag[4], afrag[4];
        #pragma unroll
        for (int ct = 0; ct < 4; ++ct)
            bfrag[ct] = *(const bf16x8*)(W_obt2 + (size_t)(w * 64 + ct * 16 + lr) * 64 + ks * 32 + lg * 8);
        #pragma unroll
        for (int rt = 0; rt < 4; ++rt)
            afrag[rt] = *(bf16x8*)&A_lds[((rt * 16 + lr) * 256 + w * 64 + ks * 32 + lg * 8) ^ aswz];
        #pragma unroll
        for (int rt = 0; rt < 4; ++rt)
            #pragma unroll
            for (int ct = 0; ct < 4; ++ct)
                acc2[rt][ct] = __builtin_amdgcn_mfma_f32_16x16x32_bf16(afrag[rt], bfrag[ct], acc2[rt][ct], 0, 0, 0);
    }
    #pragma unroll
    for (int rt = 0; rt < 4; ++rt)
        #pragma unroll
        for (int ct = 0; ct < 4; ++ct)
            #pragma unroll
            for (int r = 0; r < 4; ++r) {
                int m = rt * 16 + lg * 4 + r;
                if (full || (n0 + m) < N_NODES)
                    y[(size_t)(n0 + m) * HD + w * 64 + ct * 16 + lr] =
                        __float2bfloat16(acc2[rt][ct][r]);
            }
}

// ---------------- bucket fill: group SRC node ids by dst ----------------
__global__ __launch_bounds__(256) void fill_kernel(
    const int* __restrict__ src, const int* __restrict__ dst,
    int* __restrict__ cursor, int* __restrict__ bucket_src,
    int* __restrict__ ov_list, int* __restrict__ ov_count) {
    int e = blockIdx.x * 256 + threadIdx.x;
    if (e >= N_EDGES) return;
    int n = dst[e];
    int pos = atomicAdd(&cursor[n], 1);
    if (pos < CAP) {
        bucket_src[(size_t)n * CAP + pos] = src[e];
    } else {
        int oi = atomicAdd(ov_count, 1);
        if (oi < OVCAP) ov_list[oi] = e;
    }
}

// -------- gather aggregation, wave-per-node: out[n] = b_out + sum alpha*y ----
__global__ __launch_bounds__(256) void agg_kernel(
    const int* __restrict__ bucket_src, const int* __restrict__ cursor,
    const int* __restrict__ src, const int* __restrict__ dst,
    const int* __restrict__ ov_list, const int* __restrict__ ov_count,
    const float* __restrict__ dnorm, const float* __restrict__ b_g,
    const __hip_bfloat16* __restrict__ y, const float* __restrict__ gd,
    const float* __restrict__ gs, const float* __restrict__ b_out,
    float* __restrict__ out) {
    __shared__ float alpha_lds[4][CAP][HEADS];   // 4 KB
    __shared__ int s_lds[4][CAP];                // 1 KB
    int t = threadIdx.x;
    int wv = t >> 6, lane = t & 63;
    int n = blockIdx.x * 4 + wv;
    int deg = cursor[n];
    if (deg > CAP) deg = CAP;
    float dn = dnorm[n];

    // phase 1: per-edge alphas; lane = (edge & 15)*4 + head, 16 edges/iter
    int hd = lane & 3;
    float gdh = gd[n * HEADS + hd] + b_g[hd];
    #pragma unroll
    for (int it = 0; it < 4; ++it) {
        int ei = it * 16 + (lane >> 2);
        if (ei < deg) {
            int s = bucket_src[(size_t)n * CAP + ei];
            if (hd == 0) s_lds[wv][ei] = s;
            float _h = gdh + gs[s * HEADS + hd];
            float g = _h > 0.f ? _h : -P_L * _h;
            alpha_lds[wv][ei][hd] = g * dn * dnorm[s];
        }
    }
    __syncthreads();

    // phase 2: lane covers flattened cols lane*4..+3 (head = lane>>4)
    int h_l = lane >> 4;
    const unsigned int* yw = (const unsigned int*)y + lane * 2;
    float a0 = 0.f, a1 = 0.f, a2 = 0.f, a3 = 0.f;
    int i = 0;
    for (; i + 16 <= deg; i += 16) {
        uint2 v[16];
        float al[16];
        #pragma unroll
        for (int j = 0; j < 16; ++j) {
            int s = s_lds[wv][i + j];
            al[j] = alpha_lds[wv][i + j][h_l];
            v[j] = *(const uint2*)(yw + (size_t)s * 128);
        }
        #pragma unroll
        for (int j = 0; j < 16; ++j) {
            a0 += __uint_as_float(v[j].x << 16) * al[j];
            a1 += __uint_as_float(v[j].x & 0xffff0000u) * al[j];
            a2 += __uint_as_float(v[j].y << 16) * al[j];
            a3 += __uint_as_float(v[j].y & 0xffff0000u) * al[j];
        }
    }
    for (; i + 8 <= deg; i += 8) {
        uint2 v[8];
        float al[8];
        #pragma unroll
        for (int j = 0; j < 8; ++j) {
            int s = s_lds[wv][i + j];
            al[j] = alpha_lds[wv][i + j][h_l];
            v[j] = *(const uint2*)(yw + (size_t)s * 128);
        }
        #pragma unroll
        for (int j = 0; j < 8; ++j) {
            a0 += __uint_as_float(v[j].x << 16) * al[j];
            a1 += __uint_as_float(v[j].x & 0xffff0000u) * al[j];
            a2 += __uint_as_float(v[j].y << 16) * al[j];
            a3 += __uint_as_float(v[j].y & 0xffff0000u) * al[j];
        }
    }
    for (; i < deg; ++i) {
        int s = s_lds[wv][i];
        float al = alpha_lds[wv][i][h_l];
        uint2 vv = *(const uint2*)(yw + (size_t)s * 128);
        a0 += __uint_as_float(vv.x << 16) * al;
        a1 += __uint_as_float(vv.x & 0xffff0000u) * al;
        a2 += __uint_as_float(vv.y << 16) * al;
        a3 += __uint_as_float(vv.y & 0xffff0000u) * al;
    }

    // overflow edges (cnt ~always 0; uniform per-wave branch)
    int cnt = *ov_count;
    if (cnt > 0) {
        if (cnt > OVCAP) cnt = OVCAP;
        float gdh2 = gd[n * HEADS + h_l] + b_g[h_l];
        for (int j = 0; j < cnt; ++j) {
            int e = ov_list[j];
            if (dst[e] == n) {
                int s = src[e];
                float _h = gdh2 + gs[s * HEADS + h_l];
                float g = _h > 0.f ? _h : -P_L * _h;
                float al = g * dn * dnorm[s];
                uint2 vv = *(const uint2*)(yw + (size_t)s * 128);
                a0 += __uint_as_float(vv.x << 16) * al;
                a1 += __uint_as_float(vv.x & 0xffff0000u) * al;
                a2 += __uint_as_float(vv.y << 16) * al;
                a3 += __uint_as_float(vv.y & 0xffff0000u) * al;
            }
        }
    }

    // reduce over heads (lanes l, l^16, l^32, l^48 share oc) and store
    a0 += __shfl_xor(a0, 16, 64); a0 += __shfl_xor(a0, 32, 64);
    a1 += __shfl_xor(a1, 16, 64); a1 += __shfl_xor(a1, 32, 64);
    a2 += __shfl_xor(a2, 16, 64); a2 += __shfl_xor(a2, 32, 64);
    a3 += __shfl_xor(a3, 16, 64); a3 += __shfl_xor(a3, 32, 64);
    if (lane < 16) {
        float4 bo = *(const float4*)&b_out[lane * 4];
        float4 o;
        o.x = a0 + bo.x; o.y = a1 + bo.y; o.z = a2 + bo.z; o.w = a3 + bo.w;
        *(float4*)&out[(size_t)n * OUT_DIM + lane * 4] = o;
    }
}

extern "C" void kernel_launch(void* const* d_in, const int* in_sizes, int n_in,
                              void* d_out, int out_size, void* d_ws, size_t ws_size,
                              hipStream_t stream) {
    const float* h     = (const float*)d_in[0];
    const int*   src   = (const int*)d_in[1];
    const int*   dst   = (const int*)d_in[2];
    const float* dnorm = (const float*)d_in[3];
    const float* W_in  = (const float*)d_in[4];
    const float* b_in  = (const float*)d_in[5];
    const float* W_att = (const float*)d_in[6];
    const float* b_att = (const float*)d_in[7];
    const float* W_g   = (const float*)d_in[8];
    const float* b_g   = (const float*)d_in[9];
    const float* W_out = (const float*)d_in[10];
    const float* b_out = (const float*)d_in[11];
    float* out = (float*)d_out;

    char* ws = (char*)d_ws;
    __hip_bfloat16* y = (__hip_bfloat16*)ws;             // N*256 bf16 (25.6 MB)
    ws += (size_t)N_NODES * HD * sizeof(__hip_bfloat16);
    float* gd    = (float*)ws;  ws += (size_t)N_NODES * HEADS * sizeof(float);
    float* gs    = (float*)ws;  ws += (size_t)N_NODES * HEADS * sizeof(float);
    float* v_dst = (float*)ws;  ws += 256 * sizeof(float);
    float* v_src = (float*)ws;  ws += 256 * sizeof(float);
    float* c_dst = (float*)ws;  ws += 16;
    float* c_src = (float*)ws;  ws += 16;
    int* cursor     = (int*)ws; ws += (size_t)N_NODES * sizeof(int);
    int* ov_count   = (int*)ws; ws += 16;
    int* ov_list    = (int*)ws; ws += OVCAP * sizeof(int);
    int* bucket_src = (int*)ws; ws += (size_t)N_NODES * CAP * sizeof(int);
    short* W_bt     = (short*)ws; ws += 256 * 256 * sizeof(short);   // 128 KB
    short* W_obt2   = (short*)ws;                                    // 32 KB

    hipMemsetAsync(cursor, 0, (size_t)N_NODES * sizeof(int), stream);
    hipMemsetAsync(ov_count, 0, sizeof(int), stream);

    precompute_kernel<<<1, 256, 0, stream>>>(W_att, b_att, W_g, v_dst, v_src, c_dst, c_src);
    wconv_kernel<<<320, 256, 0, stream>>>(W_in, W_out, W_bt, W_obt2);
    fill_kernel<<<(N_EDGES + 255) / 256, 256, 0, stream>>>(src, dst, cursor, bucket_src,
                                                           ov_list, ov_count);
    node_mfma_kernel<<<(N_NODES + TILE_N - 1) / TILE_N, 256, 0, stream>>>(
        h, W_bt, W_obt2, b_in, v_dst, v_src, c_dst, c_src, y, gd, gs);
    agg_kernel<<<N_NODES / 4, 256, 0, stream>>>(bucket_src, cursor, src, dst,
                                                ov_list, ov_count, dnorm, b_g,
                                                y, gd, gs, b_out, out);
}

// Round 9
// 169.415 us; speedup vs baseline: 3.0037x; 1.0815x over previous
//
#include <hip/hip_runtime.h>
#include <hip/hip_bf16.h>

#define N_NODES 50000
#define N_EDGES 800000
#define IN_DIM 256
#define OUT_DIM 64
#define HEADS 4
#define HD 256          // HEADS*OUT_DIM
#define P_L 0.1f
#define TILE_N 64       // nodes per block in node_mfma
#define CAP 64          // per-node edge bucket capacity (expected max deg ~43)
#define OVCAP 4096      // overflow list capacity

typedef __attribute__((ext_vector_type(8))) short bf16x8;
typedef __attribute__((ext_vector_type(4))) float f32x4;

static __device__ __forceinline__ short f2bf(float f) {
    __hip_bfloat16 b = __float2bfloat16(f);
    return *(short*)&b;
}

// ---------------- precompute: fold W_att/b_att into W_g ----------------
__global__ __launch_bounds__(256) void precompute_kernel(
    const float* __restrict__ W_att, const float* __restrict__ b_att,
    const float* __restrict__ W_g,
    float* __restrict__ v_dst, float* __restrict__ v_src,
    float* __restrict__ c_dst, float* __restrict__ c_src) {
    int t = threadIdx.x;          // 0..255
    int h = t >> 6, dd = t & 63;
    float sd = 0.f, ss = 0.f;
    for (int e = 0; e < 64; ++e) {
        float w = W_att[h * 4096 + dd * 64 + e];
        sd += w * W_g[h * 128 + e];
        ss += w * W_g[h * 128 + 64 + e];
    }
    v_dst[t] = sd;
    v_src[t] = ss;
    if (dd == 0) {
        float cd = 0.f, cs = 0.f;
        for (int e = 0; e < 64; ++e) {
            float b = b_att[h * 64 + e];
            cd += b * W_g[h * 128 + e];
            cs += b * W_g[h * 128 + 64 + e];
        }
        c_dst[h] = cd;
        c_src[h] = cs;
    }
}

// ---- weight conversion ----
// W_bt[n][k]  = bf(W_in[k][n])                      (256x256)
// W_obt2[(h*64+oc)][k] = bf(W_out[h*64+k][oc])      (256x64, per-head B^T)
__global__ __launch_bounds__(256) void wconv_kernel(
    const float* __restrict__ W_in, const float* __restrict__ W_out,
    short* __restrict__ W_bt, short* __restrict__ W_obt2) {
    int b = blockIdx.x, t = threadIdx.x;
    if (b < 256) {
        W_bt[t * 256 + b] = f2bf(W_in[b * 256 + t]);
    } else {
        int flat = (b - 256) * 256 + t;        // [0, 16384)
        int k = flat & 63, oc = (flat >> 6) & 63, h = flat >> 12;
        W_obt2[flat] = f2bf(W_out[(h * 64 + k) * 64 + oc]);
    }
}

// ---------------- node transform via MFMA (+ fused out-projection y) --------
// 64 nodes/block. hh = relu(h@W_in+b); gd/gs per head; y = per-head hh@W_out.
__global__ __launch_bounds__(256, 2) void node_mfma_kernel(
    const float* __restrict__ hin, const short* __restrict__ W_bt,
    const short* __restrict__ W_obt2, const float* __restrict__ b_in,
    const float* __restrict__ v_dst, const float* __restrict__ v_src,
    const float* __restrict__ c_dst, const float* __restrict__ c_src,
    __hip_bfloat16* __restrict__ y, float* __restrict__ gd,
    float* __restrict__ gs) {
    __shared__ short A_lds[TILE_N * 256];   // 32 KB, XOR-swizzled
    int t = threadIdx.x;
    int n0 = blockIdx.x * TILE_N;
    bool full = (n0 + TILE_N) <= N_NODES;

    // ---- stage h tile (4 passes of the 16-row pattern) ----
    #pragma unroll
    for (int rr = 0; rr < 4; ++rr) {
        int r = rr * 16 + (t >> 4), c0 = (t & 15) * 16;
        int row = n0 + r;
        if (row > N_NODES - 1) row = N_NODES - 1;   // clamp (tail block)
        const float* hp = hin + (size_t)row * IN_DIM + c0;
        float fv[16];
        *(float4*)&fv[0]  = *(const float4*)(hp + 0);
        *(float4*)&fv[4]  = *(const float4*)(hp + 4);
        *(float4*)&fv[8]  = *(const float4*)(hp + 8);
        *(float4*)&fv[12] = *(const float4*)(hp + 12);
        short sv[16];
        #pragma unroll
        for (int j = 0; j < 16; ++j) sv[j] = f2bf(fv[j]);
        int swz = (r & 7) << 3;
        int base = r * 256 + c0;
        *(bf16x8*)&A_lds[(base + 0) ^ swz] = *(bf16x8*)&sv[0];
        *(bf16x8*)&A_lds[(base + 8) ^ swz] = *(bf16x8*)&sv[8];
    }
    __syncthreads();

    int l = t & 63, w = t >> 6;
    int lr = l & 15, lg = l >> 4;
    int aswz = (lr & 7) << 3;

    f32x4 acc[4][4];   // [row-tile][col-tile]
    #pragma unroll
    for (int rt = 0; rt < 4; ++rt)
        #pragma unroll
        for (int ct = 0; ct < 4; ++ct) acc[rt][ct] = (f32x4){0.f, 0.f, 0.f, 0.f};

    #pragma unroll
    for (int ks = 0; ks < 8; ++ks) {
        bf16x8 bfrag[4], afrag[4];
        #pragma unroll
        for (int ct = 0; ct < 4; ++ct)
            bfrag[ct] = *(const bf16x8*)(W_bt + (size_t)(w * 64 + ct * 16 + lr) * 256 + ks * 32 + lg * 8);
        #pragma unroll
        for (int rt = 0; rt < 4; ++rt)
            afrag[rt] = *(bf16x8*)&A_lds[((rt * 16 + lr) * 256 + ks * 32 + lg * 8) ^ aswz];
        #pragma unroll
        for (int rt = 0; rt < 4; ++rt)
            #pragma unroll
            for (int ct = 0; ct < 4; ++ct)
                acc[rt][ct] = __builtin_amdgcn_mfma_f32_16x16x32_bf16(afrag[rt], bfrag[ct], acc[rt][ct], 0, 0, 0);
    }

    // ---- epilogue: relu(+b_in) in place, gd/gs partials ----
    int col[4];
    float vd[4], vs[4], bi[4];
    #pragma unroll
    for (int ct = 0; ct < 4; ++ct) {
        col[ct] = w * 64 + ct * 16 + lr;
        bi[ct] = b_in[col[ct]];
        vd[ct] = v_dst[col[ct]];
        vs[ct] = v_src[col[ct]];
    }
    float pd[4][4], ps[4][4];   // [rt][r]
    #pragma unroll
    for (int rt = 0; rt < 4; ++rt)
        #pragma unroll
        for (int r = 0; r < 4; ++r) { pd[rt][r] = 0.f; ps[rt][r] = 0.f; }
    #pragma unroll
    for (int rt = 0; rt < 4; ++rt)
        #pragma unroll
        for (int ct = 0; ct < 4; ++ct)
            #pragma unroll
            for (int r = 0; r < 4; ++r) {
                float v = fmaxf(acc[rt][ct][r] + bi[ct], 0.f);
                acc[rt][ct][r] = v;          // reuse as hh value
                pd[rt][r] += v * vd[ct];
                ps[rt][r] += v * vs[ct];
            }
    #pragma unroll
    for (int rt = 0; rt < 4; ++rt)
        #pragma unroll
        for (int r = 0; r < 4; ++r) {
            #pragma unroll
            for (int off = 1; off < 16; off <<= 1) {
                pd[rt][r] += __shfl_xor(pd[rt][r], off, 64);
                ps[rt][r] += __shfl_xor(ps[rt][r], off, 64);
            }
        }
    if (lr == 0) {
        float cd = c_dst[w], cs = c_src[w];
        #pragma unroll
        for (int rt = 0; rt < 4; ++rt)
            #pragma unroll
            for (int r = 0; r < 4; ++r) {
                int m = rt * 16 + lg * 4 + r;
                if (full || (n0 + m) < N_NODES) {
                    gd[(n0 + m) * HEADS + w] = pd[rt][r] + cd;
                    gs[(n0 + m) * HEADS + w] = ps[rt][r] + cs;
                }
            }
    }

    // ---- restage hh into A_lds for the y-GEMM ----
    __syncthreads();   // everyone done reading input-h tile
    #pragma unroll
    for (int rt = 0; rt < 4; ++rt)
        #pragma unroll
        for (int ct = 0; ct < 4; ++ct)
            #pragma unroll
            for (int r = 0; r < 4; ++r) {
                int m = rt * 16 + lg * 4 + r;
                int idx = m * 256 + col[ct];
                A_lds[idx ^ (((lg * 4 + r) & 7) << 3)] = f2bf(acc[rt][ct][r]);
            }
    __syncthreads();

    // ---- y-GEMM: per head w, [64 nodes x 64k] @ [64k x 64oc] ----
    f32x4 acc2[4][4];
    #pragma unroll
    for (int rt = 0; rt < 4; ++rt)
        #pragma unroll
        for (int ct = 0; ct < 4; ++ct) acc2[rt][ct] = (f32x4){0.f, 0.f, 0.f, 0.f};
    #pragma unroll
    for (int ks = 0; ks < 2; ++ks) {
        bf16x8 bfrag[4], afrag[4];
        #pragma unroll
        for (int ct = 0; ct < 4; ++ct)
            bfrag[ct] = *(const bf16x8*)(W_obt2 + (size_t)(w * 64 + ct * 16 + lr) * 64 + ks * 32 + lg * 8);
        #pragma unroll
        for (int rt = 0; rt < 4; ++rt)
            afrag[rt] = *(bf16x8*)&A_lds[((rt * 16 + lr) * 256 + w * 64 + ks * 32 + lg * 8) ^ aswz];
        #pragma unroll
        for (int rt = 0; rt < 4; ++rt)
            #pragma unroll
            for (int ct = 0; ct < 4; ++ct)
                acc2[rt][ct] = __builtin_amdgcn_mfma_f32_16x16x32_bf16(afrag[rt], bfrag[ct], acc2[rt][ct], 0, 0, 0);
    }
    #pragma unroll
    for (int rt = 0; rt < 4; ++rt)
        #pragma unroll
        for (int ct = 0; ct < 4; ++ct)
            #pragma unroll
            for (int r = 0; r < 4; ++r) {
                int m = rt * 16 + lg * 4 + r;
                if (full || (n0 + m) < N_NODES)
                    y[(size_t)(n0 + m) * HD + w * 64 + ct * 16 + lr] =
                        __float2bfloat16(acc2[rt][ct][r]);
            }
}

// ---------------- bucket fill: group SRC node ids by dst ----------------
__global__ __launch_bounds__(256) void fill_kernel(
    const int* __restrict__ src, const int* __restrict__ dst,
    int* __restrict__ cursor, int* __restrict__ bucket_src,
    int* __restrict__ ov_list, int* __restrict__ ov_count) {
    int e = blockIdx.x * 256 + threadIdx.x;
    if (e >= N_EDGES) return;
    int n = dst[e];
    int pos = atomicAdd(&cursor[n], 1);
    if (pos < CAP) {
        bucket_src[(size_t)n * CAP + pos] = src[e];
    } else {
        int oi = atomicAdd(ov_count, 1);
        if (oi < OVCAP) ov_list[oi] = e;
    }
}

// -------- gather agg, barrier-free, 2 nodes/wave: out[n] = b_out + sum alpha*y
// lanes 0-31 -> node A, lanes 32-63 -> node B. Lane covers 8 cols (one uint4).
__global__ __launch_bounds__(256) void agg_kernel(
    const int* __restrict__ bucket_src, const int* __restrict__ cursor,
    const int* __restrict__ src, const int* __restrict__ dst,
    const int* __restrict__ ov_list, const int* __restrict__ ov_count,
    const float* __restrict__ dnorm, const float* __restrict__ b_g,
    const __hip_bfloat16* __restrict__ y, const float* __restrict__ gd,
    const float* __restrict__ gs, const float* __restrict__ b_out,
    float* __restrict__ out) {
    int t = threadIdx.x;
    int wv = t >> 6, lane = t & 63;
    int half = lane >> 5, sl = lane & 31;
    int n = blockIdx.x * 8 + wv * 2 + half;
    int head = sl >> 3;                       // flat col c = sl*8+j, head = c>>6
    int deg = cursor[n];
    if (deg > CAP) deg = CAP;
    float dn = dnorm[n];
    float gdh = gd[n * HEADS + head] + b_g[head];
    int degmax = max(deg, __shfl_xor(deg, 32, 64));   // other half's deg

    const uint4* yb = (const uint4*)y;        // row = 32 uint4
    const int* bp = bucket_src + (size_t)n * CAP;
    float a[8];
    #pragma unroll
    for (int j = 0; j < 8; ++j) a[j] = 0.f;

    for (int i = 0; i < degmax; i += 8) {
        // stage 1: 8 independent src-id broadcast loads
        int sarr[8];
        #pragma unroll
        for (int j = 0; j < 8; ++j) {
            int e = i + j;
            sarr[j] = (e < deg) ? bp[e] : -1;
        }
        // stage 2: dependent gathers, all independent of each other
        float gsv[8], dnv[8];
        uint4 v[8];
        #pragma unroll
        for (int j = 0; j < 8; ++j) {
            int s = sarr[j] < 0 ? 0 : sarr[j];
            gsv[j] = gs[s * HEADS + head];
            dnv[j] = dnorm[s];
            v[j] = yb[(size_t)s * 32 + sl];
        }
        // stage 3: math
        #pragma unroll
        for (int j = 0; j < 8; ++j) {
            float _h = gdh + gsv[j];
            float g = _h > 0.f ? _h : -P_L * _h;
            float al = (sarr[j] < 0) ? 0.f : g * dn * dnv[j];
            a[0] += __uint_as_float(v[j].x << 16) * al;
            a[1] += __uint_as_float(v[j].x & 0xffff0000u) * al;
            a[2] += __uint_as_float(v[j].y << 16) * al;
            a[3] += __uint_as_float(v[j].y & 0xffff0000u) * al;
            a[4] += __uint_as_float(v[j].z << 16) * al;
            a[5] += __uint_as_float(v[j].z & 0xffff0000u) * al;
            a[6] += __uint_as_float(v[j].w << 16) * al;
            a[7] += __uint_as_float(v[j].w & 0xffff0000u) * al;
        }
    }

    // overflow edges (cnt ~always 0; uniform branch, broadcast loads)
    int cnt = *ov_count;
    if (cnt > 0) {
        if (cnt > OVCAP) cnt = OVCAP;
        for (int j = 0; j < cnt; ++j) {
            int e = ov_list[j];
            if (dst[e] == n) {
                int s = src[e];
                float _h = gdh + gs[s * HEADS + head];
                float g = _h > 0.f ? _h : -P_L * _h;
                float al = g * dn * dnorm[s];
                uint4 vv = yb[(size_t)s * 32 + sl];
                a[0] += __uint_as_float(vv.x << 16) * al;
                a[1] += __uint_as_float(vv.x & 0xffff0000u) * al;
                a[2] += __uint_as_float(vv.y << 16) * al;
                a[3] += __uint_as_float(vv.y & 0xffff0000u) * al;
                a[4] += __uint_as_float(vv.z << 16) * al;
                a[5] += __uint_as_float(vv.z & 0xffff0000u) * al;
                a[6] += __uint_as_float(vv.w << 16) * al;
                a[7] += __uint_as_float(vv.w & 0xffff0000u) * al;
            }
        }
    }

    // reduce over heads: partners sl^8 (head bit0), sl^16 (head bit1); both <32
    #pragma unroll
    for (int j = 0; j < 8; ++j) {
        a[j] += __shfl_xor(a[j], 8, 64);
        a[j] += __shfl_xor(a[j], 16, 64);
    }
    // lanes sl<8 hold oc = sl*8+j
    if (sl < 8) {
        float4 b0 = *(const float4*)&b_out[sl * 8];
        float4 b1 = *(const float4*)&b_out[sl * 8 + 4];
        float4 o0, o1;
        o0.x = a[0] + b0.x; o0.y = a[1] + b0.y; o0.z = a[2] + b0.z; o0.w = a[3] + b0.w;
        o1.x = a[4] + b1.x; o1.y = a[5] + b1.y; o1.z = a[6] + b1.z; o1.w = a[7] + b1.w;
        *(float4*)&out[(size_t)n * OUT_DIM + sl * 8] = o0;
        *(float4*)&out[(size_t)n * OUT_DIM + sl * 8 + 4] = o1;
    }
}

extern "C" void kernel_launch(void* const* d_in, const int* in_sizes, int n_in,
                              void* d_out, int out_size, void* d_ws, size_t ws_size,
                              hipStream_t stream) {
    const float* h     = (const float*)d_in[0];
    const int*   src   = (const int*)d_in[1];
    const int*   dst   = (const int*)d_in[2];
    const float* dnorm = (const float*)d_in[3];
    const float* W_in  = (const float*)d_in[4];
    const float* b_in  = (const float*)d_in[5];
    const float* W_att = (const float*)d_in[6];
    const float* b_att = (const float*)d_in[7];
    const float* W_g   = (const float*)d_in[8];
    const float* b_g   = (const float*)d_in[9];
    const float* W_out = (const float*)d_in[10];
    const float* b_out = (const float*)d_in[11];
    float* out = (float*)d_out;

    char* ws = (char*)d_ws;
    __hip_bfloat16* y = (__hip_bfloat16*)ws;             // N*256 bf16 (25.6 MB)
    ws += (size_t)N_NODES * HD * sizeof(__hip_bfloat16);
    float* gd    = (float*)ws;  ws += (size_t)N_NODES * HEADS * sizeof(float);
    float* gs    = (float*)ws;  ws += (size_t)N_NODES * HEADS * sizeof(float);
    float* v_dst = (float*)ws;  ws += 256 * sizeof(float);
    float* v_src = (float*)ws;  ws += 256 * sizeof(float);
    float* c_dst = (float*)ws;  ws += 16;
    float* c_src = (float*)ws;  ws += 16;
    int* cursor     = (int*)ws; ws += (size_t)N_NODES * sizeof(int);
    int* ov_count   = (int*)ws; ws += 16;
    int* ov_list    = (int*)ws; ws += OVCAP * sizeof(int);
    int* bucket_src = (int*)ws; ws += (size_t)N_NODES * CAP * sizeof(int);
    short* W_bt     = (short*)ws; ws += 256 * 256 * sizeof(short);   // 128 KB
    short* W_obt2   = (short*)ws;                                    // 32 KB

    hipMemsetAsync(cursor, 0, (size_t)N_NODES * sizeof(int), stream);
    hipMemsetAsync(ov_count, 0, sizeof(int), stream);

    precompute_kernel<<<1, 256, 0, stream>>>(W_att, b_att, W_g, v_dst, v_src, c_dst, c_src);
    wconv_kernel<<<320, 256, 0, stream>>>(W_in, W_out, W_bt, W_obt2);
    fill_kernel<<<(N_EDGES + 255) / 256, 256, 0, stream>>>(src, dst, cursor, bucket_src,
                                                           ov_list, ov_count);
    node_mfma_kernel<<<(N_NODES + TILE_N - 1) / TILE_N, 256, 0, stream>>>(
        h, W_bt, W_obt2, b_in, v_dst, v_src, c_dst, c_src, y, gd, gs);
    agg_kernel<<<N_NODES / 8, 256, 0, stream>>>(bucket_src, cursor, src, dst,
                                                ov_list, ov_count, dnorm, b_g,
                                                y, gd, gs, b_out, out);
}